// Round 6
// baseline (788.090 us; speedup 1.0000x reference)
//
#include <hip/hip_runtime.h>
#include <math.h>

// Problem constants
#define BB 2
#define RR 4096
#define NRAY (BB*RR)            // 8192
#define SC 48
#define NSAMP (NRAY*SC)         // 393216
#define CF 32
#define HID 64
#define ODIM 33                 // 1 sigma + 32 rgb
#define PRES 256
#define PLANE_HW (PRES*PRES)    // 65536
#define RAY_START 0.1f
#define RAY_END 2.0f
#define DELTA ((RAY_END-RAY_START)/(SC-1))

// workspace layout (in floats)
#define OFF_PLANES2  ((size_t)0)
#define OFF_DEPTH_C  ((size_t)12582912)                 // 393216
#define OFF_SIGMA_C  (OFF_DEPTH_C + 393216)             // 393216
#define OFF_RGB_C    (OFF_SIGMA_C + 393216)             // 12582912
#define OFF_DEPTH_F  (OFF_RGB_C + 12582912)             // 393216
#define OFF_SIGMA_F  (OFF_DEPTH_F + 393216)             // 393216
#define OFF_RGB_F    (OFF_SIGMA_F + 393216)             // 12582912
#define OFF_MINMAX   (OFF_RGB_F + 12582912)             // 2 uints (+2 pad)
#define OFF_W2T      (OFF_MINMAX + 4)                   // 33*64 floats (w2 transposed)

typedef __attribute__((ext_vector_type(2))) float f2_t;

// packed fp32 FMA: acc.{x,y} += a.{x,y} * b.{x,y}  (one VOP3P inst = 2 FMA)
__device__ __forceinline__ void pk_fma_vv(f2_t& acc, f2_t a, f2_t b) {
    asm("v_pk_fma_f32 %0, %1, %2, %0" : "+v"(acc) : "v"(a), "v"(b));
}
// variant with the (single allowed) scalar operand: b must be wave-uniform
__device__ __forceinline__ void pk_fma_vs(f2_t& acc, f2_t a, f2_t b) {
    asm("v_pk_fma_f32 %0, %1, %2, %0" : "+v"(acc) : "v"(a), "s"(b));
}
// dword of 2 packed bf16 -> f2_t {lo, hi}
__device__ __forceinline__ f2_t bfpair(unsigned int u) {
    union { unsigned int i; float f; } lo, hi;
    lo.i = u << 16;
    hi.i = u & 0xffff0000u;
    f2_t r; r.x = lo.f; r.y = hi.f;
    return r;
}

__device__ __forceinline__ float softplusf(float x) {
    return fmaxf(x, 0.f) + __logf(1.f + __expf(-fabsf(x)));
}
__device__ __forceinline__ float sigact(float o) {
    float r = __builtin_amdgcn_rcpf(1.f + __expf(-o));
    return fmaf(1.002f, r, -0.001f);
}
__device__ __forceinline__ unsigned short f2bf(float f) {
    union { float f; unsigned int u; } v; v.f = f;
    unsigned int r = v.u + 0x7fffu + ((v.u >> 16) & 1u);   // RNE
    return (unsigned short)(r >> 16);
}
__device__ __forceinline__ unsigned int pack2(float lo, float hi) {
    return (unsigned int)f2bf(lo) | ((unsigned int)f2bf(hi) << 16);
}

// ---------------------------------------------------------------------------
// Kernel 1: planes_bf[bp][y][x][c] = bf16(planes[bp][c][y][x]).
// Pure transpose+convert. Also: w2t = w2^T.
__global__ __launch_bounds__(256) void precompute2(
    const float* __restrict__ planes, const float* __restrict__ w2,
    unsigned short* __restrict__ planes_bf, float* __restrict__ w2t)
{
    if (blockIdx.x == 0 && threadIdx.x < ODIM) {
        int k = threadIdx.x;
        for (int j = 0; j < HID; ++j) w2t[k * HID + j] = w2[j * ODIM + k];
    }
    int row = blockIdx.x;
    int bp = row >> 8, y = row & 255;
    int x = threadIdx.x;
    const float* src = planes + (size_t)bp * CF * PLANE_HW + (size_t)y * PRES + x;
    unsigned short* dst = planes_bf + ((size_t)bp * PLANE_HW + (size_t)(y << 8) + x) * CF;
    #pragma unroll
    for (int q = 0; q < 4; ++q) {
        uint4 u;
        u.x = pack2(src[(size_t)(q*8+0)*PLANE_HW], src[(size_t)(q*8+1)*PLANE_HW]);
        u.y = pack2(src[(size_t)(q*8+2)*PLANE_HW], src[(size_t)(q*8+3)*PLANE_HW]);
        u.z = pack2(src[(size_t)(q*8+4)*PLANE_HW], src[(size_t)(q*8+5)*PLANE_HW]);
        u.w = pack2(src[(size_t)(q*8+6)*PLANE_HW], src[(size_t)(q*8+7)*PLANE_HW]);
        ((uint4*)dst)[q] = u;
    }
}

// ---------------------------------------------------------------------------
// Kernel 2 (R18): producer/consumer wave specialization. R17 showed gather
// (memory phase) and GEMM (VALU phase) serialize per block (VALU 47%, occ 57%,
// HBM 15% -- nothing saturated). Block = 512 thr: waves 0-3 gather tile t
// (R17's quad-coalesced code) into double-buffered LDS; waves 4-7 run R17's
// GEMM+epilogue on tile t-1. 2 barriers/tile; no loads live across barriers
// (producers consume their own loads first), so the barrier vmcnt-drain is
// free. T=4 tiles/block -> grid 768 = exactly 3 blocks/CU (LDS 50.7 KB).
__global__ __launch_bounds__(512) void sample_mlp(
    const unsigned short* __restrict__ planes_bf,
    const float* __restrict__ depths_in,   // fine pass
    const float* __restrict__ noise,       // coarse pass
    float* __restrict__ depth_out,         // coarse pass
    const float* __restrict__ origins,
    const float* __restrict__ dirs,
    const float* __restrict__ w1,
    const float* __restrict__ b1,
    const float* __restrict__ w2t, const float* __restrict__ b2,
    float* __restrict__ sigma_out, float* __restrict__ rgb_out,
    int coarse)
{
    __shared__ __align__(16) float s_feat[2][32][130];   // 33280 B, double-buffered
    __shared__ __align__(8)  float s_part[2][64][34];    // 17408 B, o-partials

    const int T = 4;
    int tid = threadIdx.x;
    int tile0 = blockIdx.x * T;
    bool prod = tid < 256;                 // waves 0-3 produce, 4-7 consume

    // producer ids
    int qg = tid >> 2, sl = tid & 3;       // qg in [0,64): samples 2qg,2qg+1
    // consumer ids (wave-uniform; garbage-but-unused for producer waves)
    int lane = tid & 63;
    int cwv = (tid >> 6) & 3;
    int halfu = __builtin_amdgcn_readfirstlane(cwv & 1);
    int pairu = __builtin_amdgcn_readfirstlane(cwv >> 1);

    float o[ODIM + 1];                     // consumer epilogue carry

    for (int t = 0; t <= T; ++t) {
        if (prod) {
            if (t < T) {
                int s0 = (tile0 + t) * 128 + 2 * qg;   // pair never straddles a ray
                int ray = s0 / SC;
                int b = ray >> 12;

                float dep[2];
                if (coarse) {
                    int sb = s0 - ray * SC;
                    dep[0] = RAY_START + (float)sb * DELTA + noise[s0] * DELTA;
                    dep[1] = RAY_START + (float)(sb + 1) * DELTA + noise[s0 + 1] * DELTA;
                    if (sl == 0) { depth_out[s0] = dep[0]; depth_out[s0 + 1] = dep[1]; }
                } else {
                    dep[0] = depths_in[s0];
                    dep[1] = depths_in[s0 + 1];
                }

                float ox = origins[ray*3+0], oy = origins[ray*3+1], oz = origins[ray*3+2];
                float dx = dirs[ray*3+0],    dy = dirs[ray*3+1],    dz = dirs[ray*3+2];

                f2_t fa[2][4];
                #pragma unroll
                for (int k = 0; k < 2; ++k)
                    #pragma unroll
                    for (int j = 0; j < 4; ++j) fa[k][j] = (f2_t){0.f, 0.f};

                #pragma unroll
                for (int k = 0; k < 2; ++k) {
                    float cx = (ox + dep[k]*dx) * 0.5f;
                    float cy = (oy + dep[k]*dy) * 0.5f;
                    float cz = (oz + dep[k]*dz) * 0.5f;
                    #pragma unroll
                    for (int p = 0; p < 3; ++p) {
                        float gx = (p == 0) ? cx : (p == 1) ? cy : cz;
                        float gy = (p == 0) ? cy : (p == 1) ? cz : cx;
                        float x = fmaf(gx, 128.f, 127.5f);
                        float y = fmaf(gy, 128.f, 127.5f);
                        float x0f = floorf(x), y0f = floorf(y);
                        float wx1 = x - x0f, wy1 = y - y0f;
                        int x0 = (int)x0f, y0 = (int)y0f;
                        const unsigned short* pb = planes_bf + (size_t)(b*3 + p) * PLANE_HW * CF;
                        #pragma unroll
                        for (int cyi = 0; cyi < 2; ++cyi) {
                            #pragma unroll
                            for (int cxi = 0; cxi < 2; ++cxi) {
                                int xi = x0 + cxi, yi = y0 + cyi;
                                float wgt = ((cyi ? wy1 : 1.f - wy1) * (cxi ? wx1 : 1.f - wx1)) * (1.f/3.f);
                                if (xi < 0 || xi > 255 || yi < 0 || yi > 255) wgt = 0.f;
                                int xc = min(max(xi, 0), 255), yc = min(max(yi, 0), 255);
                                const uint4* tp = (const uint4*)(pb + (size_t)((yc << 8) + xc) * CF);
                                uint4 v = tp[sl];       // quad covers the 64B texel in 1 inst
                                f2_t wp2; wp2.x = wgt; wp2.y = wgt;
                                pk_fma_vv(fa[k][0], bfpair(v.x), wp2);
                                pk_fma_vv(fa[k][1], bfpair(v.y), wp2);
                                pk_fma_vv(fa[k][2], bfpair(v.z), wp2);
                                pk_fma_vv(fa[k][3], bfpair(v.w), wp2);
                            }
                        }
                    }
                }

                float (*fb)[130] = s_feat[t & 1];
                #pragma unroll
                for (int k = 0; k < 2; ++k)
                    #pragma unroll
                    for (int j = 0; j < 4; ++j) {
                        fb[8*sl + 2*j    ][2*qg + k] = fa[k][j].x;
                        fb[8*sl + 2*j + 1][2*qg + k] = fa[k][j].y;
                    }
            }
        } else if (t >= 1) {
            // consumer: GEMM for tile t-1
            int ls = pairu * 64 + lane;
            const float (*fb)[130] = s_feat[(t - 1) & 1];

            f2_t h2[16];
            const f2_t* b1p = (const f2_t*)(b1 + halfu * 32);
            #pragma unroll
            for (int j = 0; j < 16; ++j) h2[j] = b1p[j];

            #pragma unroll
            for (int c = 0; c < CF; ++c) {
                float fc = fb[c][ls];
                f2_t fc2; fc2.x = fc; fc2.y = fc;
                const f2_t* wp = (const f2_t*)(w1 + c * HID + halfu * 32);
                #pragma unroll
                for (int j = 0; j < 16; ++j) pk_fma_vs(h2[j], fc2, wp[j]);
            }
            #pragma unroll
            for (int j = 0; j < 16; ++j) {
                h2[j].x = softplusf(h2[j].x);
                h2[j].y = softplusf(h2[j].y);
            }

            const f2_t* wbase = (const f2_t*)(w2t + halfu * 32);
            #pragma unroll
            for (int k = 0; k < ODIM; ++k) {
                const f2_t* wp = wbase + k * (HID/2);
                f2_t acc = (f2_t){0.f, 0.f};
                #pragma unroll
                for (int j = 0; j < 16; ++j) pk_fma_vs(acc, h2[j], wp[j]);
                o[k] = acc.x + acc.y;
            }
            o[ODIM] = 0.f;

            if (halfu) {
                f2_t* dstp = (f2_t*)&s_part[pairu][lane][0];
                #pragma unroll
                for (int j = 0; j < 17; ++j) {
                    f2_t v; v.x = o[2*j]; v.y = o[2*j+1];
                    dstp[j] = v;
                }
            }
        }
        __syncthreads();   // B1: feat[t] published; o-partials published

        if (!prod && t >= 1 && halfu == 0) {
            int ls = pairu * 64 + lane;
            int sample = (tile0 + t - 1) * 128 + ls;
            const f2_t* srcp = (const f2_t*)&s_part[pairu][lane][0];
            #pragma unroll
            for (int j = 0; j < 17; ++j) {
                f2_t v = srcp[j];
                o[2*j]   += v.x;
                o[2*j+1] += v.y;
            }
            #pragma unroll
            for (int k = 0; k < ODIM; ++k) o[k] += b2[k];

            sigma_out[sample] = o[0];
            float4* ro = (float4*)(rgb_out + (size_t)sample * 32);
            #pragma unroll
            for (int q = 0; q < 8; ++q) {
                float4 v;
                v.x = sigact(o[1 + q*4 + 0]);
                v.y = sigact(o[1 + q*4 + 1]);
                v.z = sigact(o[1 + q*4 + 2]);
                v.w = sigact(o[1 + q*4 + 3]);
                ro[q] = v;
            }
        }
        __syncthreads();   // B2: s_part reads done; feat[t-1] reads done
    }
}

// ---------------------------------------------------------------------------
// Kernel 3: importance sampling, one wave per ray; block-level minmax to
// scratch (bmin/bmax staged in rgb_f, overwritten later by the fine pass).
__global__ __launch_bounds__(256) void importance_kernel(
    const float* __restrict__ depth_c, const float* __restrict__ sigma_c,
    const float* __restrict__ noise_imp, float* __restrict__ depth_f,
    float* __restrict__ bmin, float* __restrict__ bmax)
{
    __shared__ float s_cdf[4][46];
    __shared__ float s_bins[4][47];
    __shared__ float s_red[8];
    int wave = threadIdx.x >> 6, lane = threadIdx.x & 63;
    int ray = blockIdx.x * 4 + wave;

    const float* d  = depth_c + (size_t)ray * SC;
    const float* sg = sigma_c + (size_t)ray * SC;
    float dval = (lane < SC) ? d[lane] : 0.f;
    float sval = (lane < SC) ? sg[lane] : 0.f;
    float dnext = __shfl_down(dval, 1);
    float snext = __shfl_down(sval, 1);

    float a = 0.f;
    if (lane < SC-1) {
        float dens = softplusf(0.5f * (sval + snext) - 1.f);
        a = 1.f - expf(-dens * (dnext - dval));
    }
    float f = (lane < SC-1) ? (1.f - a + 1e-10f) : 1.f;
    float incl = f;
    #pragma unroll
    for (int off = 1; off < 64; off <<= 1) {
        float t = __shfl_up(incl, off);
        if (lane >= off) incl *= t;
    }
    float T = (lane == 0) ? 1.f : __shfl_up(incl, 1);
    float w = a * T;
    float wm1 = __shfl_up(w, 1);
    float wp1 = __shfl_down(w, 1);
    float wn = 0.5f * (fmaxf(wm1, w) + fmaxf(w, wp1)) + 0.01f + 1e-5f;
    float g = (lane >= 1 && lane <= 45) ? wn : 0.f;
    float incl2 = g;
    #pragma unroll
    for (int off = 1; off < 64; off <<= 1) {
        float t = __shfl_up(incl2, off);
        if (lane >= off) incl2 += t;
    }
    float sum = __shfl(incl2, 45);
    if (lane == 0) s_cdf[wave][0] = 0.f;
    else if (lane <= 45) s_cdf[wave][lane] = incl2 / sum;
    if (lane < SC-1) s_bins[wave][lane] = 0.5f * (dval + dnext);
    __syncthreads();

    float fmn = 1e30f, fmx = -1e30f;
    if (lane < SC) {
        float u = noise_imp[(size_t)ray * SC + lane];
        int inds = 0;
        #pragma unroll
        for (int t = 0; t < 46; ++t) inds += (s_cdf[wave][t] <= u) ? 1 : 0;
        int below = max(inds - 1, 0), above = min(inds, 45);
        float cb = s_cdf[wave][below], ca = s_cdf[wave][above];
        float bb = s_bins[wave][below], ba = s_bins[wave][above];
        float den = (ca - cb < 1e-5f) ? 1.f : (ca - cb);
        float s = bb + (u - cb) / den * (ba - bb);
        depth_f[(size_t)ray * SC + lane] = s;
        fmn = s; fmx = s;
    }
    float d0 = __shfl(dval, 0), dlast = __shfl(dval, SC-1);
    fmn = fminf(fmn, d0); fmx = fmaxf(fmx, dlast);
    #pragma unroll
    for (int off = 32; off >= 1; off >>= 1) {
        fmn = fminf(fmn, __shfl_xor(fmn, off));
        fmx = fmaxf(fmx, __shfl_xor(fmx, off));
    }
    if (lane == 0) { s_red[wave] = fmn; s_red[4 + wave] = fmx; }
    __syncthreads();
    if (threadIdx.x == 0) {
        bmin[blockIdx.x] = fminf(fminf(s_red[0], s_red[1]), fminf(s_red[2], s_red[3]));
        bmax[blockIdx.x] = fmaxf(fmaxf(s_red[4], s_red[5]), fmaxf(s_red[6], s_red[7]));
    }
}

// ---------------------------------------------------------------------------
// Kernel 3b: fold 2048 per-block (min,max) pairs into minmax[0..1]. 1 block.
__global__ __launch_bounds__(1024) void reduce_minmax(
    const float* __restrict__ bmin, const float* __restrict__ bmax,
    unsigned int* __restrict__ minmax)
{
    int tid = threadIdx.x;
    float mn = fminf(bmin[tid], bmin[tid + 1024]);
    float mx = fmaxf(bmax[tid], bmax[tid + 1024]);
    #pragma unroll
    for (int off = 32; off >= 1; off >>= 1) {
        mn = fminf(mn, __shfl_xor(mn, off));
        mx = fmaxf(mx, __shfl_xor(mx, off));
    }
    __shared__ float smn[16], smx[16];
    int wv = tid >> 6;
    if ((tid & 63) == 0) { smn[wv] = mn; smx[wv] = mx; }
    __syncthreads();
    if (tid == 0) {
        float m = smn[0], M = smx[0];
        #pragma unroll
        for (int i = 1; i < 16; ++i) { m = fminf(m, smn[i]); M = fmaxf(M, smx[i]); }
        minmax[0] = __float_as_uint(m);
        minmax[1] = __float_as_uint(M);
    }
}

// ---------------------------------------------------------------------------
// Kernel 4: merge coarse+fine (stable rank sort of 96), final ray-march.
// (unchanged known-passing serial-cumprod version)
__global__ __launch_bounds__(256) void final_march(
    const float* __restrict__ depth_c, const float* __restrict__ sigma_c,
    const float* __restrict__ rgb_c,
    const float* __restrict__ depth_f, const float* __restrict__ sigma_f,
    const float* __restrict__ rgb_f,
    const unsigned int* __restrict__ minmax,
    float* __restrict__ out)
{
    __shared__ float dall[4][96];
    __shared__ float sall[4][96];
    __shared__ float dsrt[4][96];
    __shared__ float ssrt[4][96];
    __shared__ int   perm[4][96];
    __shared__ float al[4][96];

    int wid = threadIdx.x >> 6, lane = threadIdx.x & 63;
    int ray = blockIdx.x * 4 + wid;

    for (int j = lane; j < 96; j += 64) {
        float dv, sv;
        if (j < 48) { dv = depth_c[(size_t)ray*48 + j]; sv = sigma_c[(size_t)ray*48 + j]; }
        else        { dv = depth_f[(size_t)ray*48 + j-48]; sv = sigma_f[(size_t)ray*48 + j-48]; }
        dall[wid][j] = dv; sall[wid][j] = sv;
    }
    __syncthreads();
    for (int j = lane; j < 96; j += 64) {
        float dj = dall[wid][j];
        int rank = 0;
        for (int k = 0; k < 96; ++k) {
            float dk = dall[wid][k];
            rank += (dk < dj || (dk == dj && k < j)) ? 1 : 0;
        }
        dsrt[wid][rank] = dj;
        ssrt[wid][rank] = sall[wid][j];
        perm[wid][rank] = j;
    }
    __syncthreads();
    for (int i = lane; i < 95; i += 64) {
        float dlt = dsrt[wid][i+1] - dsrt[wid][i];
        float dens = softplusf(0.5f * (ssrt[wid][i] + ssrt[wid][i+1]) - 1.f);
        al[wid][i] = 1.f - expf(-dens * dlt);
    }
    __syncthreads();
    if (lane == 0) {
        float T = 1.f, wsum = 0.f, dsum = 0.f;
        for (int i = 0; i < 95; ++i) {
            float a = al[wid][i];
            float wloc = a * T;
            T *= 1.f - a + 1e-10f;
            al[wid][i] = wloc;
            wsum += wloc;
            dsum += wloc * 0.5f * (dsrt[wid][i] + dsrt[wid][i+1]);
        }
        float depth = dsum / wsum;
        if (isnan(depth)) depth = INFINITY;
        float gmn = __uint_as_float(minmax[0]);
        float gmx = __uint_as_float(minmax[1]);
        depth = fminf(fmaxf(depth, gmn), gmx);
        out[262144 + ray] = depth;
        out[270336 + ray] = wsum;
        out[278528 + ray] = T;
    }
    __syncthreads();
    int k = lane & 31, half = lane >> 5;
    int i0 = half * 48, i1 = half ? 95 : 48;
    const float* rc = rgb_c + (size_t)ray * 48 * 32;
    const float* rf = rgb_f + (size_t)ray * 48 * 32;
    float acc = 0.f;
    int j0 = perm[wid][i0];
    float cur = (j0 < 48) ? rc[j0*32 + k] : rf[(j0-48)*32 + k];
    for (int i = i0; i < i1; ++i) {
        int jn = perm[wid][i+1];
        float nxt = (jn < 48) ? rc[jn*32 + k] : rf[(jn-48)*32 + k];
        acc += al[wid][i] * (cur + nxt);
        cur = nxt;
    }
    acc *= 0.5f;
    acc += __shfl_xor(acc, 32);
    if (half == 0) out[(size_t)ray * 32 + k] = acc * 2.f - 1.f;
}

// ---------------------------------------------------------------------------
extern "C" void kernel_launch(void* const* d_in, const int* in_sizes, int n_in,
                              void* d_out, int out_size, void* d_ws, size_t ws_size,
                              hipStream_t stream) {
    const float* planes      = (const float*)d_in[0];
    const float* origins     = (const float*)d_in[1];
    const float* dirs        = (const float*)d_in[2];
    const float* w1          = (const float*)d_in[3];
    const float* b1          = (const float*)d_in[4];
    const float* w2          = (const float*)d_in[5];
    const float* b2          = (const float*)d_in[6];
    const float* noise_strat = (const float*)d_in[7];
    const float* noise_imp   = (const float*)d_in[8];
    float* out = (float*)d_out;
    float* ws  = (float*)d_ws;

    unsigned short* planes_bf = (unsigned short*)(ws + OFF_PLANES2);
    float* depth_c = ws + OFF_DEPTH_C;
    float* sigma_c = ws + OFF_SIGMA_C;
    float* rgb_c   = ws + OFF_RGB_C;
    float* depth_f = ws + OFF_DEPTH_F;
    float* sigma_f = ws + OFF_SIGMA_F;
    float* rgb_f   = ws + OFF_RGB_F;
    unsigned int* minmax = (unsigned int*)(ws + OFF_MINMAX);
    float* w2t = ws + OFF_W2T;
    // per-block minmax scratch: staged in rgb_f (overwritten later by fine pass)
    float* bmin = rgb_f;
    float* bmax = rgb_f + 2048;

    precompute2<<<1536, 256, 0, stream>>>(planes, w2, planes_bf, w2t);
    sample_mlp<<<NSAMP/512, 512, 0, stream>>>(planes_bf, nullptr, noise_strat, depth_c,
                                              origins, dirs, w1, b1, w2t, b2,
                                              sigma_c, rgb_c, 1);
    importance_kernel<<<NRAY/4, 256, 0, stream>>>(depth_c, sigma_c, noise_imp,
                                                  depth_f, bmin, bmax);
    reduce_minmax<<<1, 1024, 0, stream>>>(bmin, bmax, minmax);
    sample_mlp<<<NSAMP/512, 512, 0, stream>>>(planes_bf, depth_f, nullptr, nullptr,
                                              origins, dirs, w1, b1, w2t, b2,
                                              sigma_f, rgb_f, 0);
    final_march<<<NRAY/4, 256, 0, stream>>>(depth_c, sigma_c, rgb_c,
                                            depth_f, sigma_f, rgb_f, minmax, out);
}

// Round 7
// 358.538 us; speedup vs baseline: 2.1981x; 2.1981x over previous
//
#include <hip/hip_runtime.h>
#include <math.h>

// Problem constants
#define BB 2
#define RR 4096
#define NRAY (BB*RR)            // 8192
#define SC 48
#define NSAMP (NRAY*SC)         // 393216
#define CF 32
#define HID 64
#define ODIM 33                 // 1 sigma + 32 rgb
#define PRES 256
#define PLANE_HW (PRES*PRES)    // 65536
#define RAY_START 0.1f
#define RAY_END 2.0f
#define DELTA ((RAY_END-RAY_START)/(SC-1))

// workspace layout (in floats)
#define OFF_PLANES2  ((size_t)0)
#define OFF_DEPTH_C  ((size_t)12582912)                 // 393216
#define OFF_SIGMA_C  (OFF_DEPTH_C + 393216)             // 393216
#define OFF_RGB_C    (OFF_SIGMA_C + 393216)             // 12582912
#define OFF_DEPTH_F  (OFF_RGB_C + 12582912)             // 393216
#define OFF_SIGMA_F  (OFF_DEPTH_F + 393216)             // 393216
#define OFF_RGB_F    (OFF_SIGMA_F + 393216)             // 12582912
#define OFF_MINMAX   (OFF_RGB_F + 12582912)             // 2 uints (+2 pad)
#define OFF_W2T      (OFF_MINMAX + 4)                   // 33*64 floats (w2 transposed)

typedef __attribute__((ext_vector_type(2))) float f2_t;

// packed fp32 FMA: acc.{x,y} += a.{x,y} * b.{x,y}  (one VOP3P inst = 2 FMA)
__device__ __forceinline__ void pk_fma_vv(f2_t& acc, f2_t a, f2_t b) {
    asm("v_pk_fma_f32 %0, %1, %2, %0" : "+v"(acc) : "v"(a), "v"(b));
}
// variant with the (single allowed) scalar operand: b must be wave-uniform
__device__ __forceinline__ void pk_fma_vs(f2_t& acc, f2_t a, f2_t b) {
    asm("v_pk_fma_f32 %0, %1, %2, %0" : "+v"(acc) : "v"(a), "s"(b));
}
// dword of 2 packed bf16 -> f2_t {lo, hi}
__device__ __forceinline__ f2_t bfpair(unsigned int u) {
    union { unsigned int i; float f; } lo, hi;
    lo.i = u << 16;
    hi.i = u & 0xffff0000u;
    f2_t r; r.x = lo.f; r.y = hi.f;
    return r;
}

__device__ __forceinline__ float softplusf(float x) {
    return fmaxf(x, 0.f) + __logf(1.f + __expf(-fabsf(x)));
}
__device__ __forceinline__ float sigact(float o) {
    float r = __builtin_amdgcn_rcpf(1.f + __expf(-o));
    return fmaf(1.002f, r, -0.001f);
}
__device__ __forceinline__ unsigned short f2bf(float f) {
    union { float f; unsigned int u; } v; v.f = f;
    unsigned int r = v.u + 0x7fffu + ((v.u >> 16) & 1u);   // RNE
    return (unsigned short)(r >> 16);
}
__device__ __forceinline__ unsigned int pack2(float lo, float hi) {
    return (unsigned int)f2bf(lo) | ((unsigned int)f2bf(hi) << 16);
}

// ---------------------------------------------------------------------------
// Kernel 1: planes_bf[bp][y][x][c] = bf16(planes[bp][c][y][x]).
// Pure transpose+convert. Also: w2t = w2^T.
__global__ __launch_bounds__(256) void precompute2(
    const float* __restrict__ planes, const float* __restrict__ w2,
    unsigned short* __restrict__ planes_bf, float* __restrict__ w2t)
{
    if (blockIdx.x == 0 && threadIdx.x < ODIM) {
        int k = threadIdx.x;
        for (int j = 0; j < HID; ++j) w2t[k * HID + j] = w2[j * ODIM + k];
    }
    int row = blockIdx.x;
    int bp = row >> 8, y = row & 255;
    int x = threadIdx.x;
    const float* src = planes + (size_t)bp * CF * PLANE_HW + (size_t)y * PRES + x;
    unsigned short* dst = planes_bf + ((size_t)bp * PLANE_HW + (size_t)(y << 8) + x) * CF;
    #pragma unroll
    for (int q = 0; q < 4; ++q) {
        uint4 u;
        u.x = pack2(src[(size_t)(q*8+0)*PLANE_HW], src[(size_t)(q*8+1)*PLANE_HW]);
        u.y = pack2(src[(size_t)(q*8+2)*PLANE_HW], src[(size_t)(q*8+3)*PLANE_HW]);
        u.z = pack2(src[(size_t)(q*8+4)*PLANE_HW], src[(size_t)(q*8+5)*PLANE_HW]);
        u.w = pack2(src[(size_t)(q*8+6)*PLANE_HW], src[(size_t)(q*8+7)*PLANE_HW]);
        ((uint4*)dst)[q] = u;
    }
}

// ---------------------------------------------------------------------------
// Kernel 2 (R19): R17's quad-coalesced gather + GEMM, but 128-thread blocks
// (2 waves, 64 samples). R18's specialization failed (375 us: occupancy 23%,
// half the waves gathering); R17's residual was phase-convoy at 3 barriers x
// 4 waves with high gather-latency variance (25MB table thrashes 4MB/XCD L2,
// FETCH=79MB -> L3-latency stalls). Smaller blocks: 8.7KB LDS -> 16 blocks/CU
// (2x R17), 2-wave barriers, finer block-level phase mixing so gather latency
// hides under other blocks' GEMM.
__global__ __launch_bounds__(128, 3) void sample_mlp(
    const unsigned short* __restrict__ planes_bf,
    const float* __restrict__ depths_in,   // fine pass
    const float* __restrict__ noise,       // coarse pass
    float* __restrict__ depth_out,         // coarse pass
    const float* __restrict__ origins,
    const float* __restrict__ dirs,
    const float* __restrict__ w1,
    const float* __restrict__ b1,
    const float* __restrict__ w2t, const float* __restrict__ b2,
    float* __restrict__ sigma_out, float* __restrict__ rgb_out,
    int coarse)
{
    __shared__ __align__(16) char s_mem[8704];
    float (*s_feat)[66] = (float (*)[66])s_mem;      // [32][66] = 8448 B
    float (*s_part)[34] = (float (*)[34])s_mem;      // [64][34] = 8704 B (reused)

    int tid = threadIdx.x;

    // ---- gather phase: quad qg = tid>>2 handles samples 2qg, 2qg+1 ----
    {
        int qg = tid >> 2, sl = tid & 3;             // qg in [0,32)
        int s0 = blockIdx.x * 64 + 2 * qg;           // even -> pair never straddles a ray
        int ray = s0 / SC;
        int b = ray >> 12;

        float dep[2];
        if (coarse) {
            int sb = s0 - ray * SC;
            dep[0] = RAY_START + (float)sb * DELTA + noise[s0] * DELTA;
            dep[1] = RAY_START + (float)(sb + 1) * DELTA + noise[s0 + 1] * DELTA;
            if (sl == 0) { depth_out[s0] = dep[0]; depth_out[s0 + 1] = dep[1]; }
        } else {
            dep[0] = depths_in[s0];
            dep[1] = depths_in[s0 + 1];
        }

        float ox = origins[ray*3+0], oy = origins[ray*3+1], oz = origins[ray*3+2];
        float dx = dirs[ray*3+0],    dy = dirs[ray*3+1],    dz = dirs[ray*3+2];

        f2_t fa[2][4];
        #pragma unroll
        for (int k = 0; k < 2; ++k)
            #pragma unroll
            for (int j = 0; j < 4; ++j) fa[k][j] = (f2_t){0.f, 0.f};

        #pragma unroll
        for (int k = 0; k < 2; ++k) {
            float cx = (ox + dep[k]*dx) * 0.5f;
            float cy = (oy + dep[k]*dy) * 0.5f;
            float cz = (oz + dep[k]*dz) * 0.5f;
            #pragma unroll
            for (int p = 0; p < 3; ++p) {
                float gx = (p == 0) ? cx : (p == 1) ? cy : cz;
                float gy = (p == 0) ? cy : (p == 1) ? cz : cx;
                float x = fmaf(gx, 128.f, 127.5f);
                float y = fmaf(gy, 128.f, 127.5f);
                float x0f = floorf(x), y0f = floorf(y);
                float wx1 = x - x0f, wy1 = y - y0f;
                int x0 = (int)x0f, y0 = (int)y0f;
                const unsigned short* pb = planes_bf + (size_t)(b*3 + p) * PLANE_HW * CF;
                #pragma unroll
                for (int cyi = 0; cyi < 2; ++cyi) {
                    #pragma unroll
                    for (int cxi = 0; cxi < 2; ++cxi) {
                        int xi = x0 + cxi, yi = y0 + cyi;
                        float wgt = ((cyi ? wy1 : 1.f - wy1) * (cxi ? wx1 : 1.f - wx1)) * (1.f/3.f);
                        if (xi < 0 || xi > 255 || yi < 0 || yi > 255) wgt = 0.f;
                        int xc = min(max(xi, 0), 255), yc = min(max(yi, 0), 255);
                        const uint4* tp = (const uint4*)(pb + (size_t)((yc << 8) + xc) * CF);
                        uint4 v = tp[sl];            // quad covers the 64B texel in 1 inst
                        f2_t wp2; wp2.x = wgt; wp2.y = wgt;
                        pk_fma_vv(fa[k][0], bfpair(v.x), wp2);
                        pk_fma_vv(fa[k][1], bfpair(v.y), wp2);
                        pk_fma_vv(fa[k][2], bfpair(v.z), wp2);
                        pk_fma_vv(fa[k][3], bfpair(v.w), wp2);
                    }
                }
            }
        }

        // stash: lane owns channels [8sl, 8sl+8) for its 2 samples
        #pragma unroll
        for (int k = 0; k < 2; ++k)
            #pragma unroll
            for (int j = 0; j < 4; ++j) {
                s_feat[8*sl + 2*j    ][2*qg + k] = fa[k][j].x;
                s_feat[8*sl + 2*j + 1][2*qg + k] = fa[k][j].y;
            }
    }
    __syncthreads();

    // ---- GEMM phase: wave pair splits hidden dim (halfu wave-uniform) ----
    int lane = tid & 63;
    int halfu = __builtin_amdgcn_readfirstlane(tid >> 6);  // SGPR: scalar weight loads
    int sample = blockIdx.x * 64 + lane;

    f2_t h2[16];
    const f2_t* b1p = (const f2_t*)(b1 + halfu * 32);
    #pragma unroll
    for (int j = 0; j < 16; ++j) h2[j] = b1p[j];

    #pragma unroll
    for (int c = 0; c < CF; ++c) {
        float fc = s_feat[c][lane];
        f2_t fc2; fc2.x = fc; fc2.y = fc;
        const f2_t* wp = (const f2_t*)(w1 + c * HID + halfu * 32);
        #pragma unroll
        for (int j = 0; j < 16; ++j) pk_fma_vs(h2[j], fc2, wp[j]);
    }
    #pragma unroll
    for (int j = 0; j < 16; ++j) {
        h2[j].x = softplusf(h2[j].x);
        h2[j].y = softplusf(h2[j].y);
    }

    // partial GEMM2 over own 32 hidden channels; w2t row halves via SGPR offset.
    float o[ODIM + 1];   // pad to 34 for f2 LDS traffic
    const f2_t* wbase = (const f2_t*)(w2t + halfu * 32);
    #pragma unroll
    for (int k = 0; k < ODIM; ++k) {
        const f2_t* wp = wbase + k * (HID/2);
        f2_t acc = (f2_t){0.f, 0.f};
        #pragma unroll
        for (int j = 0; j < 16; ++j) pk_fma_vs(acc, h2[j], wp[j]);
        o[k] = acc.x + acc.y;
    }
    o[ODIM] = 0.f;

    __syncthreads();   // s_feat reads done; s_mem reused for o-partials
    if (halfu) {
        f2_t* dstp = (f2_t*)&s_part[lane][0];
        #pragma unroll
        for (int j = 0; j < 17; ++j) {
            f2_t v; v.x = o[2*j]; v.y = o[2*j+1];
            dstp[j] = v;
        }
    }
    __syncthreads();
    if (!halfu) {
        const f2_t* srcp = (const f2_t*)&s_part[lane][0];
        #pragma unroll
        for (int j = 0; j < 17; ++j) {
            f2_t v = srcp[j];
            o[2*j]   += v.x;
            o[2*j+1] += v.y;
        }
        #pragma unroll
        for (int k = 0; k < ODIM; ++k) o[k] += b2[k];

        sigma_out[sample] = o[0];
        float4* ro = (float4*)(rgb_out + (size_t)sample * 32);
        #pragma unroll
        for (int q = 0; q < 8; ++q) {
            float4 v;
            v.x = sigact(o[1 + q*4 + 0]);
            v.y = sigact(o[1 + q*4 + 1]);
            v.z = sigact(o[1 + q*4 + 2]);
            v.w = sigact(o[1 + q*4 + 3]);
            ro[q] = v;
        }
    }
}

// ---------------------------------------------------------------------------
// Kernel 3: importance sampling, one wave per ray; block-level minmax to
// scratch (bmin/bmax staged in rgb_f, overwritten later by the fine pass).
__global__ __launch_bounds__(256) void importance_kernel(
    const float* __restrict__ depth_c, const float* __restrict__ sigma_c,
    const float* __restrict__ noise_imp, float* __restrict__ depth_f,
    float* __restrict__ bmin, float* __restrict__ bmax)
{
    __shared__ float s_cdf[4][46];
    __shared__ float s_bins[4][47];
    __shared__ float s_red[8];
    int wave = threadIdx.x >> 6, lane = threadIdx.x & 63;
    int ray = blockIdx.x * 4 + wave;

    const float* d  = depth_c + (size_t)ray * SC;
    const float* sg = sigma_c + (size_t)ray * SC;
    float dval = (lane < SC) ? d[lane] : 0.f;
    float sval = (lane < SC) ? sg[lane] : 0.f;
    float dnext = __shfl_down(dval, 1);
    float snext = __shfl_down(sval, 1);

    float a = 0.f;
    if (lane < SC-1) {
        float dens = softplusf(0.5f * (sval + snext) - 1.f);
        a = 1.f - expf(-dens * (dnext - dval));
    }
    float f = (lane < SC-1) ? (1.f - a + 1e-10f) : 1.f;
    float incl = f;
    #pragma unroll
    for (int off = 1; off < 64; off <<= 1) {
        float t = __shfl_up(incl, off);
        if (lane >= off) incl *= t;
    }
    float T = (lane == 0) ? 1.f : __shfl_up(incl, 1);
    float w = a * T;
    float wm1 = __shfl_up(w, 1);
    float wp1 = __shfl_down(w, 1);
    float wn = 0.5f * (fmaxf(wm1, w) + fmaxf(w, wp1)) + 0.01f + 1e-5f;
    float g = (lane >= 1 && lane <= 45) ? wn : 0.f;
    float incl2 = g;
    #pragma unroll
    for (int off = 1; off < 64; off <<= 1) {
        float t = __shfl_up(incl2, off);
        if (lane >= off) incl2 += t;
    }
    float sum = __shfl(incl2, 45);
    if (lane == 0) s_cdf[wave][0] = 0.f;
    else if (lane <= 45) s_cdf[wave][lane] = incl2 / sum;
    if (lane < SC-1) s_bins[wave][lane] = 0.5f * (dval + dnext);
    __syncthreads();

    float fmn = 1e30f, fmx = -1e30f;
    if (lane < SC) {
        float u = noise_imp[(size_t)ray * SC + lane];
        int inds = 0;
        #pragma unroll
        for (int t = 0; t < 46; ++t) inds += (s_cdf[wave][t] <= u) ? 1 : 0;
        int below = max(inds - 1, 0), above = min(inds, 45);
        float cb = s_cdf[wave][below], ca = s_cdf[wave][above];
        float bb = s_bins[wave][below], ba = s_bins[wave][above];
        float den = (ca - cb < 1e-5f) ? 1.f : (ca - cb);
        float s = bb + (u - cb) / den * (ba - bb);
        depth_f[(size_t)ray * SC + lane] = s;
        fmn = s; fmx = s;
    }
    float d0 = __shfl(dval, 0), dlast = __shfl(dval, SC-1);
    fmn = fminf(fmn, d0); fmx = fmaxf(fmx, dlast);
    #pragma unroll
    for (int off = 32; off >= 1; off >>= 1) {
        fmn = fminf(fmn, __shfl_xor(fmn, off));
        fmx = fmaxf(fmx, __shfl_xor(fmx, off));
    }
    if (lane == 0) { s_red[wave] = fmn; s_red[4 + wave] = fmx; }
    __syncthreads();
    if (threadIdx.x == 0) {
        bmin[blockIdx.x] = fminf(fminf(s_red[0], s_red[1]), fminf(s_red[2], s_red[3]));
        bmax[blockIdx.x] = fmaxf(fmaxf(s_red[4], s_red[5]), fmaxf(s_red[6], s_red[7]));
    }
}

// ---------------------------------------------------------------------------
// Kernel 3b: fold 2048 per-block (min,max) pairs into minmax[0..1]. 1 block.
__global__ __launch_bounds__(1024) void reduce_minmax(
    const float* __restrict__ bmin, const float* __restrict__ bmax,
    unsigned int* __restrict__ minmax)
{
    int tid = threadIdx.x;
    float mn = fminf(bmin[tid], bmin[tid + 1024]);
    float mx = fmaxf(bmax[tid], bmax[tid + 1024]);
    #pragma unroll
    for (int off = 32; off >= 1; off >>= 1) {
        mn = fminf(mn, __shfl_xor(mn, off));
        mx = fmaxf(mx, __shfl_xor(mx, off));
    }
    __shared__ float smn[16], smx[16];
    int wv = tid >> 6;
    if ((tid & 63) == 0) { smn[wv] = mn; smx[wv] = mx; }
    __syncthreads();
    if (tid == 0) {
        float m = smn[0], M = smx[0];
        #pragma unroll
        for (int i = 1; i < 16; ++i) { m = fminf(m, smn[i]); M = fmaxf(M, smx[i]); }
        minmax[0] = __float_as_uint(m);
        minmax[1] = __float_as_uint(M);
    }
}

// ---------------------------------------------------------------------------
// Kernel 4: merge coarse+fine (stable rank sort of 96), final ray-march.
// (unchanged known-passing serial-cumprod version)
__global__ __launch_bounds__(256) void final_march(
    const float* __restrict__ depth_c, const float* __restrict__ sigma_c,
    const float* __restrict__ rgb_c,
    const float* __restrict__ depth_f, const float* __restrict__ sigma_f,
    const float* __restrict__ rgb_f,
    const unsigned int* __restrict__ minmax,
    float* __restrict__ out)
{
    __shared__ float dall[4][96];
    __shared__ float sall[4][96];
    __shared__ float dsrt[4][96];
    __shared__ float ssrt[4][96];
    __shared__ int   perm[4][96];
    __shared__ float al[4][96];

    int wid = threadIdx.x >> 6, lane = threadIdx.x & 63;
    int ray = blockIdx.x * 4 + wid;

    for (int j = lane; j < 96; j += 64) {
        float dv, sv;
        if (j < 48) { dv = depth_c[(size_t)ray*48 + j]; sv = sigma_c[(size_t)ray*48 + j]; }
        else        { dv = depth_f[(size_t)ray*48 + j-48]; sv = sigma_f[(size_t)ray*48 + j-48]; }
        dall[wid][j] = dv; sall[wid][j] = sv;
    }
    __syncthreads();
    for (int j = lane; j < 96; j += 64) {
        float dj = dall[wid][j];
        int rank = 0;
        for (int k = 0; k < 96; ++k) {
            float dk = dall[wid][k];
            rank += (dk < dj || (dk == dj && k < j)) ? 1 : 0;
        }
        dsrt[wid][rank] = dj;
        ssrt[wid][rank] = sall[wid][j];
        perm[wid][rank] = j;
    }
    __syncthreads();
    for (int i = lane; i < 95; i += 64) {
        float dlt = dsrt[wid][i+1] - dsrt[wid][i];
        float dens = softplusf(0.5f * (ssrt[wid][i] + ssrt[wid][i+1]) - 1.f);
        al[wid][i] = 1.f - expf(-dens * dlt);
    }
    __syncthreads();
    if (lane == 0) {
        float T = 1.f, wsum = 0.f, dsum = 0.f;
        for (int i = 0; i < 95; ++i) {
            float a = al[wid][i];
            float wloc = a * T;
            T *= 1.f - a + 1e-10f;
            al[wid][i] = wloc;
            wsum += wloc;
            dsum += wloc * 0.5f * (dsrt[wid][i] + dsrt[wid][i+1]);
        }
        float depth = dsum / wsum;
        if (isnan(depth)) depth = INFINITY;
        float gmn = __uint_as_float(minmax[0]);
        float gmx = __uint_as_float(minmax[1]);
        depth = fminf(fmaxf(depth, gmn), gmx);
        out[262144 + ray] = depth;
        out[270336 + ray] = wsum;
        out[278528 + ray] = T;
    }
    __syncthreads();
    int k = lane & 31, half = lane >> 5;
    int i0 = half * 48, i1 = half ? 95 : 48;
    const float* rc = rgb_c + (size_t)ray * 48 * 32;
    const float* rf = rgb_f + (size_t)ray * 48 * 32;
    float acc = 0.f;
    int j0 = perm[wid][i0];
    float cur = (j0 < 48) ? rc[j0*32 + k] : rf[(j0-48)*32 + k];
    for (int i = i0; i < i1; ++i) {
        int jn = perm[wid][i+1];
        float nxt = (jn < 48) ? rc[jn*32 + k] : rf[(jn-48)*32 + k];
        acc += al[wid][i] * (cur + nxt);
        cur = nxt;
    }
    acc *= 0.5f;
    acc += __shfl_xor(acc, 32);
    if (half == 0) out[(size_t)ray * 32 + k] = acc * 2.f - 1.f;
}

// ---------------------------------------------------------------------------
extern "C" void kernel_launch(void* const* d_in, const int* in_sizes, int n_in,
                              void* d_out, int out_size, void* d_ws, size_t ws_size,
                              hipStream_t stream) {
    const float* planes      = (const float*)d_in[0];
    const float* origins     = (const float*)d_in[1];
    const float* dirs        = (const float*)d_in[2];
    const float* w1          = (const float*)d_in[3];
    const float* b1          = (const float*)d_in[4];
    const float* w2          = (const float*)d_in[5];
    const float* b2          = (const float*)d_in[6];
    const float* noise_strat = (const float*)d_in[7];
    const float* noise_imp   = (const float*)d_in[8];
    float* out = (float*)d_out;
    float* ws  = (float*)d_ws;

    unsigned short* planes_bf = (unsigned short*)(ws + OFF_PLANES2);
    float* depth_c = ws + OFF_DEPTH_C;
    float* sigma_c = ws + OFF_SIGMA_C;
    float* rgb_c   = ws + OFF_RGB_C;
    float* depth_f = ws + OFF_DEPTH_F;
    float* sigma_f = ws + OFF_SIGMA_F;
    float* rgb_f   = ws + OFF_RGB_F;
    unsigned int* minmax = (unsigned int*)(ws + OFF_MINMAX);
    float* w2t = ws + OFF_W2T;
    // per-block minmax scratch: staged in rgb_f (overwritten later by fine pass)
    float* bmin = rgb_f;
    float* bmax = rgb_f + 2048;

    precompute2<<<1536, 256, 0, stream>>>(planes, w2, planes_bf, w2t);
    sample_mlp<<<NSAMP/64, 128, 0, stream>>>(planes_bf, nullptr, noise_strat, depth_c,
                                             origins, dirs, w1, b1, w2t, b2,
                                             sigma_c, rgb_c, 1);
    importance_kernel<<<NRAY/4, 256, 0, stream>>>(depth_c, sigma_c, noise_imp,
                                                  depth_f, bmin, bmax);
    reduce_minmax<<<1, 1024, 0, stream>>>(bmin, bmax, minmax);
    sample_mlp<<<NSAMP/64, 128, 0, stream>>>(planes_bf, depth_f, nullptr, nullptr,
                                             origins, dirs, w1, b1, w2t, b2,
                                             sigma_f, rgb_f, 0);
    final_march<<<NRAY/4, 256, 0, stream>>>(depth_c, sigma_c, rgb_c,
                                            depth_f, sigma_f, rgb_f, minmax, out);
}

// Round 8
// 346.324 us; speedup vs baseline: 2.2756x; 1.0353x over previous
//
#include <hip/hip_runtime.h>
#include <math.h>

// Problem constants
#define BB 2
#define RR 4096
#define NRAY (BB*RR)            // 8192
#define SC 48
#define NSAMP (NRAY*SC)         // 393216
#define CF 32
#define HID 64
#define ODIM 33                 // 1 sigma + 32 rgb
#define PRES 256
#define PLANE_HW (PRES*PRES)    // 65536
#define RAY_START 0.1f
#define RAY_END 2.0f
#define DELTA ((RAY_END-RAY_START)/(SC-1))

// workspace layout (in floats)
#define OFF_PLANES2  ((size_t)0)
#define OFF_DEPTH_C  ((size_t)12582912)                 // 393216
#define OFF_SIGMA_C  (OFF_DEPTH_C + 393216)             // 393216
#define OFF_RGB_C    (OFF_SIGMA_C + 393216)             // 12582912
#define OFF_DEPTH_F  (OFF_RGB_C + 12582912)             // 393216
#define OFF_SIGMA_F  (OFF_DEPTH_F + 393216)             // 393216
#define OFF_RGB_F    (OFF_SIGMA_F + 393216)             // 12582912
#define OFF_MINMAX   (OFF_RGB_F + 12582912)             // 2 uints (+2 pad)
#define OFF_W2T      (OFF_MINMAX + 4)                   // 33*64 floats (w2 transposed)

typedef __attribute__((ext_vector_type(2))) float f2_t;

// packed fp32 FMA: acc.{x,y} += a.{x,y} * b.{x,y}  (one VOP3P inst = 2 FMA)
__device__ __forceinline__ void pk_fma_vv(f2_t& acc, f2_t a, f2_t b) {
    asm("v_pk_fma_f32 %0, %1, %2, %0" : "+v"(acc) : "v"(a), "v"(b));
}
// variant with the (single allowed) scalar operand: b must be wave-uniform
__device__ __forceinline__ void pk_fma_vs(f2_t& acc, f2_t a, f2_t b) {
    asm("v_pk_fma_f32 %0, %1, %2, %0" : "+v"(acc) : "v"(a), "s"(b));
}
// dword of 2 packed bf16 -> f2_t {lo, hi}
__device__ __forceinline__ f2_t bfpair(unsigned int u) {
    union { unsigned int i; float f; } lo, hi;
    lo.i = u << 16;
    hi.i = u & 0xffff0000u;
    f2_t r; r.x = lo.f; r.y = hi.f;
    return r;
}

__device__ __forceinline__ float softplusf(float x) {
    return fmaxf(x, 0.f) + __logf(1.f + __expf(-fabsf(x)));
}
__device__ __forceinline__ float sigact(float o) {
    float r = __builtin_amdgcn_rcpf(1.f + __expf(-o));
    return fmaf(1.002f, r, -0.001f);
}
__device__ __forceinline__ unsigned short f2bf(float f) {
    union { float f; unsigned int u; } v; v.f = f;
    unsigned int r = v.u + 0x7fffu + ((v.u >> 16) & 1u);   // RNE
    return (unsigned short)(r >> 16);
}
__device__ __forceinline__ unsigned int pack2(float lo, float hi) {
    return (unsigned int)f2bf(lo) | ((unsigned int)f2bf(hi) << 16);
}

// ---------------------------------------------------------------------------
// Kernel 1: planes_bf[bp][y][x][c] = bf16(planes[bp][c][y][x]).
// Pure transpose+convert. Also: w2t = w2^T.
__global__ __launch_bounds__(256) void precompute2(
    const float* __restrict__ planes, const float* __restrict__ w2,
    unsigned short* __restrict__ planes_bf, float* __restrict__ w2t)
{
    if (blockIdx.x == 0 && threadIdx.x < ODIM) {
        int k = threadIdx.x;
        for (int j = 0; j < HID; ++j) w2t[k * HID + j] = w2[j * ODIM + k];
    }
    int row = blockIdx.x;
    int bp = row >> 8, y = row & 255;
    int x = threadIdx.x;
    const float* src = planes + (size_t)bp * CF * PLANE_HW + (size_t)y * PRES + x;
    unsigned short* dst = planes_bf + ((size_t)bp * PLANE_HW + (size_t)(y << 8) + x) * CF;
    #pragma unroll
    for (int q = 0; q < 4; ++q) {
        uint4 u;
        u.x = pack2(src[(size_t)(q*8+0)*PLANE_HW], src[(size_t)(q*8+1)*PLANE_HW]);
        u.y = pack2(src[(size_t)(q*8+2)*PLANE_HW], src[(size_t)(q*8+3)*PLANE_HW]);
        u.z = pack2(src[(size_t)(q*8+4)*PLANE_HW], src[(size_t)(q*8+5)*PLANE_HW]);
        u.w = pack2(src[(size_t)(q*8+6)*PLANE_HW], src[(size_t)(q*8+7)*PLANE_HW]);
        ((uint4*)dst)[q] = u;
    }
}

// ---------------------------------------------------------------------------
// Kernel 2 (R20): R19 structure; epilogue rewritten. Read-side opts (R12->R19:
// 96->48->24 requests, 24->12 lines) left dur ~constant (126/127/112/107us) --
// fingerprints a store-side floor: rgb stores were 16B pieces at 128B lane
// stride, so every 64B sector was assembled from 4 different instructions
// (L2 partial-write merges; bytes look clean in WRITE_SIZE, cost invisible).
// Fix: wave0 stages sigact'd rgb into its LDS row, then ALL 128 threads
// copy the block's 64x32 floats (8KB contiguous) as coalesced float4 stores.
__global__ __launch_bounds__(128, 3) void sample_mlp(
    const unsigned short* __restrict__ planes_bf,
    const float* __restrict__ depths_in,   // fine pass
    const float* __restrict__ noise,       // coarse pass
    float* __restrict__ depth_out,         // coarse pass
    const float* __restrict__ origins,
    const float* __restrict__ dirs,
    const float* __restrict__ w1,
    const float* __restrict__ b1,
    const float* __restrict__ w2t, const float* __restrict__ b2,
    float* __restrict__ sigma_out, float* __restrict__ rgb_out,
    int coarse)
{
    __shared__ __align__(16) char s_mem[8704];
    float (*s_feat)[66] = (float (*)[66])s_mem;      // [32][66] = 8448 B
    float (*s_part)[34] = (float (*)[34])s_mem;      // [64][34] = 8704 B (reused)

    int tid = threadIdx.x;

    // ---- gather phase: quad qg = tid>>2 handles samples 2qg, 2qg+1 ----
    {
        int qg = tid >> 2, sl = tid & 3;             // qg in [0,32)
        int s0 = blockIdx.x * 64 + 2 * qg;           // even -> pair never straddles a ray
        int ray = s0 / SC;
        int b = ray >> 12;

        float dep[2];
        if (coarse) {
            int sb = s0 - ray * SC;
            dep[0] = RAY_START + (float)sb * DELTA + noise[s0] * DELTA;
            dep[1] = RAY_START + (float)(sb + 1) * DELTA + noise[s0 + 1] * DELTA;
            if (sl == 0) { depth_out[s0] = dep[0]; depth_out[s0 + 1] = dep[1]; }
        } else {
            dep[0] = depths_in[s0];
            dep[1] = depths_in[s0 + 1];
        }

        float ox = origins[ray*3+0], oy = origins[ray*3+1], oz = origins[ray*3+2];
        float dx = dirs[ray*3+0],    dy = dirs[ray*3+1],    dz = dirs[ray*3+2];

        f2_t fa[2][4];
        #pragma unroll
        for (int k = 0; k < 2; ++k)
            #pragma unroll
            for (int j = 0; j < 4; ++j) fa[k][j] = (f2_t){0.f, 0.f};

        #pragma unroll
        for (int k = 0; k < 2; ++k) {
            float cx = (ox + dep[k]*dx) * 0.5f;
            float cy = (oy + dep[k]*dy) * 0.5f;
            float cz = (oz + dep[k]*dz) * 0.5f;
            #pragma unroll
            for (int p = 0; p < 3; ++p) {
                float gx = (p == 0) ? cx : (p == 1) ? cy : cz;
                float gy = (p == 0) ? cy : (p == 1) ? cz : cx;
                float x = fmaf(gx, 128.f, 127.5f);
                float y = fmaf(gy, 128.f, 127.5f);
                float x0f = floorf(x), y0f = floorf(y);
                float wx1 = x - x0f, wy1 = y - y0f;
                int x0 = (int)x0f, y0 = (int)y0f;
                const unsigned short* pb = planes_bf + (size_t)(b*3 + p) * PLANE_HW * CF;
                #pragma unroll
                for (int cyi = 0; cyi < 2; ++cyi) {
                    #pragma unroll
                    for (int cxi = 0; cxi < 2; ++cxi) {
                        int xi = x0 + cxi, yi = y0 + cyi;
                        float wgt = ((cyi ? wy1 : 1.f - wy1) * (cxi ? wx1 : 1.f - wx1)) * (1.f/3.f);
                        if (xi < 0 || xi > 255 || yi < 0 || yi > 255) wgt = 0.f;
                        int xc = min(max(xi, 0), 255), yc = min(max(yi, 0), 255);
                        const uint4* tp = (const uint4*)(pb + (size_t)((yc << 8) + xc) * CF);
                        uint4 v = tp[sl];            // quad covers the 64B texel in 1 inst
                        f2_t wp2; wp2.x = wgt; wp2.y = wgt;
                        pk_fma_vv(fa[k][0], bfpair(v.x), wp2);
                        pk_fma_vv(fa[k][1], bfpair(v.y), wp2);
                        pk_fma_vv(fa[k][2], bfpair(v.z), wp2);
                        pk_fma_vv(fa[k][3], bfpair(v.w), wp2);
                    }
                }
            }
        }

        // stash: lane owns channels [8sl, 8sl+8) for its 2 samples
        #pragma unroll
        for (int k = 0; k < 2; ++k)
            #pragma unroll
            for (int j = 0; j < 4; ++j) {
                s_feat[8*sl + 2*j    ][2*qg + k] = fa[k][j].x;
                s_feat[8*sl + 2*j + 1][2*qg + k] = fa[k][j].y;
            }
    }
    __syncthreads();

    // ---- GEMM phase: wave pair splits hidden dim (halfu wave-uniform) ----
    int lane = tid & 63;
    int halfu = __builtin_amdgcn_readfirstlane(tid >> 6);  // SGPR: scalar weight loads
    int sample = blockIdx.x * 64 + lane;

    f2_t h2[16];
    const f2_t* b1p = (const f2_t*)(b1 + halfu * 32);
    #pragma unroll
    for (int j = 0; j < 16; ++j) h2[j] = b1p[j];

    #pragma unroll
    for (int c = 0; c < CF; ++c) {
        float fc = s_feat[c][lane];
        f2_t fc2; fc2.x = fc; fc2.y = fc;
        const f2_t* wp = (const f2_t*)(w1 + c * HID + halfu * 32);
        #pragma unroll
        for (int j = 0; j < 16; ++j) pk_fma_vs(h2[j], fc2, wp[j]);
    }
    #pragma unroll
    for (int j = 0; j < 16; ++j) {
        h2[j].x = softplusf(h2[j].x);
        h2[j].y = softplusf(h2[j].y);
    }

    // partial GEMM2 over own 32 hidden channels; w2t row halves via SGPR offset.
    float o[ODIM + 1];   // pad to 34 for f2 LDS traffic
    const f2_t* wbase = (const f2_t*)(w2t + halfu * 32);
    #pragma unroll
    for (int k = 0; k < ODIM; ++k) {
        const f2_t* wp = wbase + k * (HID/2);
        f2_t acc = (f2_t){0.f, 0.f};
        #pragma unroll
        for (int j = 0; j < 16; ++j) pk_fma_vs(acc, h2[j], wp[j]);
        o[k] = acc.x + acc.y;
    }
    o[ODIM] = 0.f;

    __syncthreads();   // s_feat reads done; s_mem reused for o-partials
    if (halfu) {
        f2_t* dstp = (f2_t*)&s_part[lane][0];
        #pragma unroll
        for (int j = 0; j < 17; ++j) {
            f2_t v; v.x = o[2*j]; v.y = o[2*j+1];
            dstp[j] = v;
        }
    }
    __syncthreads();
    if (!halfu) {
        const f2_t* srcp = (const f2_t*)&s_part[lane][0];
        #pragma unroll
        for (int j = 0; j < 17; ++j) {
            f2_t v = srcp[j];
            o[2*j]   += v.x;
            o[2*j+1] += v.y;
        }
        #pragma unroll
        for (int k = 0; k < ODIM; ++k) o[k] += b2[k];

        sigma_out[sample] = o[0];       // 64 consecutive floats: coalesced

        // stage sigact'd rgb into OWN LDS row (overwrites partials; row-local)
        float* row = &s_part[lane][0];
        #pragma unroll
        for (int k = 0; k < 32; ++k) row[k] = sigact(o[1 + k]);
    }
    __syncthreads();   // rgb staged for all 64 samples

    // cooperative fully-coalesced rgb store: 64 samples x 32 floats = 8 KB
    {
        float4* dst = (float4*)(rgb_out + (size_t)blockIdx.x * 64 * 32);
        #pragma unroll
        for (int i = 0; i < 4; ++i) {
            int flat4 = i * 128 + tid;               // float4 index 0..511
            int s = flat4 >> 3, cq = flat4 & 7;
            f2_t a = *(const f2_t*)&s_part[s][cq * 4];
            f2_t bq = *(const f2_t*)&s_part[s][cq * 4 + 2];
            float4 v; v.x = a.x; v.y = a.y; v.z = bq.x; v.w = bq.y;
            dst[flat4] = v;                          // consecutive lanes -> consecutive 16B
        }
    }
}

// ---------------------------------------------------------------------------
// Kernel 3: importance sampling, one wave per ray; block-level minmax to
// scratch (bmin/bmax staged in rgb_f, overwritten later by the fine pass).
__global__ __launch_bounds__(256) void importance_kernel(
    const float* __restrict__ depth_c, const float* __restrict__ sigma_c,
    const float* __restrict__ noise_imp, float* __restrict__ depth_f,
    float* __restrict__ bmin, float* __restrict__ bmax)
{
    __shared__ float s_cdf[4][46];
    __shared__ float s_bins[4][47];
    __shared__ float s_red[8];
    int wave = threadIdx.x >> 6, lane = threadIdx.x & 63;
    int ray = blockIdx.x * 4 + wave;

    const float* d  = depth_c + (size_t)ray * SC;
    const float* sg = sigma_c + (size_t)ray * SC;
    float dval = (lane < SC) ? d[lane] : 0.f;
    float sval = (lane < SC) ? sg[lane] : 0.f;
    float dnext = __shfl_down(dval, 1);
    float snext = __shfl_down(sval, 1);

    float a = 0.f;
    if (lane < SC-1) {
        float dens = softplusf(0.5f * (sval + snext) - 1.f);
        a = 1.f - expf(-dens * (dnext - dval));
    }
    float f = (lane < SC-1) ? (1.f - a + 1e-10f) : 1.f;
    float incl = f;
    #pragma unroll
    for (int off = 1; off < 64; off <<= 1) {
        float t = __shfl_up(incl, off);
        if (lane >= off) incl *= t;
    }
    float T = (lane == 0) ? 1.f : __shfl_up(incl, 1);
    float w = a * T;
    float wm1 = __shfl_up(w, 1);
    float wp1 = __shfl_down(w, 1);
    float wn = 0.5f * (fmaxf(wm1, w) + fmaxf(w, wp1)) + 0.01f + 1e-5f;
    float g = (lane >= 1 && lane <= 45) ? wn : 0.f;
    float incl2 = g;
    #pragma unroll
    for (int off = 1; off < 64; off <<= 1) {
        float t = __shfl_up(incl2, off);
        if (lane >= off) incl2 += t;
    }
    float sum = __shfl(incl2, 45);
    if (lane == 0) s_cdf[wave][0] = 0.f;
    else if (lane <= 45) s_cdf[wave][lane] = incl2 / sum;
    if (lane < SC-1) s_bins[wave][lane] = 0.5f * (dval + dnext);
    __syncthreads();

    float fmn = 1e30f, fmx = -1e30f;
    if (lane < SC) {
        float u = noise_imp[(size_t)ray * SC + lane];
        int inds = 0;
        #pragma unroll
        for (int t = 0; t < 46; ++t) inds += (s_cdf[wave][t] <= u) ? 1 : 0;
        int below = max(inds - 1, 0), above = min(inds, 45);
        float cb = s_cdf[wave][below], ca = s_cdf[wave][above];
        float bb = s_bins[wave][below], ba = s_bins[wave][above];
        float den = (ca - cb < 1e-5f) ? 1.f : (ca - cb);
        float s = bb + (u - cb) / den * (ba - bb);
        depth_f[(size_t)ray * SC + lane] = s;
        fmn = s; fmx = s;
    }
    float d0 = __shfl(dval, 0), dlast = __shfl(dval, SC-1);
    fmn = fminf(fmn, d0); fmx = fmaxf(fmx, dlast);
    #pragma unroll
    for (int off = 32; off >= 1; off >>= 1) {
        fmn = fminf(fmn, __shfl_xor(fmn, off));
        fmx = fmaxf(fmx, __shfl_xor(fmx, off));
    }
    if (lane == 0) { s_red[wave] = fmn; s_red[4 + wave] = fmx; }
    __syncthreads();
    if (threadIdx.x == 0) {
        bmin[blockIdx.x] = fminf(fminf(s_red[0], s_red[1]), fminf(s_red[2], s_red[3]));
        bmax[blockIdx.x] = fmaxf(fmaxf(s_red[4], s_red[5]), fmaxf(s_red[6], s_red[7]));
    }
}

// ---------------------------------------------------------------------------
// Kernel 3b: fold 2048 per-block (min,max) pairs into minmax[0..1]. 1 block.
__global__ __launch_bounds__(1024) void reduce_minmax(
    const float* __restrict__ bmin, const float* __restrict__ bmax,
    unsigned int* __restrict__ minmax)
{
    int tid = threadIdx.x;
    float mn = fminf(bmin[tid], bmin[tid + 1024]);
    float mx = fmaxf(bmax[tid], bmax[tid + 1024]);
    #pragma unroll
    for (int off = 32; off >= 1; off >>= 1) {
        mn = fminf(mn, __shfl_xor(mn, off));
        mx = fmaxf(mx, __shfl_xor(mx, off));
    }
    __shared__ float smn[16], smx[16];
    int wv = tid >> 6;
    if ((tid & 63) == 0) { smn[wv] = mn; smx[wv] = mx; }
    __syncthreads();
    if (tid == 0) {
        float m = smn[0], M = smx[0];
        #pragma unroll
        for (int i = 1; i < 16; ++i) { m = fminf(m, smn[i]); M = fmaxf(M, smx[i]); }
        minmax[0] = __float_as_uint(m);
        minmax[1] = __float_as_uint(M);
    }
}

// ---------------------------------------------------------------------------
// Kernel 4: merge coarse+fine (stable rank sort of 96), final ray-march.
// (unchanged known-passing serial-cumprod version)
__global__ __launch_bounds__(256) void final_march(
    const float* __restrict__ depth_c, const float* __restrict__ sigma_c,
    const float* __restrict__ rgb_c,
    const float* __restrict__ depth_f, const float* __restrict__ sigma_f,
    const float* __restrict__ rgb_f,
    const unsigned int* __restrict__ minmax,
    float* __restrict__ out)
{
    __shared__ float dall[4][96];
    __shared__ float sall[4][96];
    __shared__ float dsrt[4][96];
    __shared__ float ssrt[4][96];
    __shared__ int   perm[4][96];
    __shared__ float al[4][96];

    int wid = threadIdx.x >> 6, lane = threadIdx.x & 63;
    int ray = blockIdx.x * 4 + wid;

    for (int j = lane; j < 96; j += 64) {
        float dv, sv;
        if (j < 48) { dv = depth_c[(size_t)ray*48 + j]; sv = sigma_c[(size_t)ray*48 + j]; }
        else        { dv = depth_f[(size_t)ray*48 + j-48]; sv = sigma_f[(size_t)ray*48 + j-48]; }
        dall[wid][j] = dv; sall[wid][j] = sv;
    }
    __syncthreads();
    for (int j = lane; j < 96; j += 64) {
        float dj = dall[wid][j];
        int rank = 0;
        for (int k = 0; k < 96; ++k) {
            float dk = dall[wid][k];
            rank += (dk < dj || (dk == dj && k < j)) ? 1 : 0;
        }
        dsrt[wid][rank] = dj;
        ssrt[wid][rank] = sall[wid][j];
        perm[wid][rank] = j;
    }
    __syncthreads();
    for (int i = lane; i < 95; i += 64) {
        float dlt = dsrt[wid][i+1] - dsrt[wid][i];
        float dens = softplusf(0.5f * (ssrt[wid][i] + ssrt[wid][i+1]) - 1.f);
        al[wid][i] = 1.f - expf(-dens * dlt);
    }
    __syncthreads();
    if (lane == 0) {
        float T = 1.f, wsum = 0.f, dsum = 0.f;
        for (int i = 0; i < 95; ++i) {
            float a = al[wid][i];
            float wloc = a * T;
            T *= 1.f - a + 1e-10f;
            al[wid][i] = wloc;
            wsum += wloc;
            dsum += wloc * 0.5f * (dsrt[wid][i] + dsrt[wid][i+1]);
        }
        float depth = dsum / wsum;
        if (isnan(depth)) depth = INFINITY;
        float gmn = __uint_as_float(minmax[0]);
        float gmx = __uint_as_float(minmax[1]);
        depth = fminf(fmaxf(depth, gmn), gmx);
        out[262144 + ray] = depth;
        out[270336 + ray] = wsum;
        out[278528 + ray] = T;
    }
    __syncthreads();
    int k = lane & 31, half = lane >> 5;
    int i0 = half * 48, i1 = half ? 95 : 48;
    const float* rc = rgb_c + (size_t)ray * 48 * 32;
    const float* rf = rgb_f + (size_t)ray * 48 * 32;
    float acc = 0.f;
    int j0 = perm[wid][i0];
    float cur = (j0 < 48) ? rc[j0*32 + k] : rf[(j0-48)*32 + k];
    for (int i = i0; i < i1; ++i) {
        int jn = perm[wid][i+1];
        float nxt = (jn < 48) ? rc[jn*32 + k] : rf[(jn-48)*32 + k];
        acc += al[wid][i] * (cur + nxt);
        cur = nxt;
    }
    acc *= 0.5f;
    acc += __shfl_xor(acc, 32);
    if (half == 0) out[(size_t)ray * 32 + k] = acc * 2.f - 1.f;
}

// ---------------------------------------------------------------------------
extern "C" void kernel_launch(void* const* d_in, const int* in_sizes, int n_in,
                              void* d_out, int out_size, void* d_ws, size_t ws_size,
                              hipStream_t stream) {
    const float* planes      = (const float*)d_in[0];
    const float* origins     = (const float*)d_in[1];
    const float* dirs        = (const float*)d_in[2];
    const float* w1          = (const float*)d_in[3];
    const float* b1          = (const float*)d_in[4];
    const float* w2          = (const float*)d_in[5];
    const float* b2          = (const float*)d_in[6];
    const float* noise_strat = (const float*)d_in[7];
    const float* noise_imp   = (const float*)d_in[8];
    float* out = (float*)d_out;
    float* ws  = (float*)d_ws;

    unsigned short* planes_bf = (unsigned short*)(ws + OFF_PLANES2);
    float* depth_c = ws + OFF_DEPTH_C;
    float* sigma_c = ws + OFF_SIGMA_C;
    float* rgb_c   = ws + OFF_RGB_C;
    float* depth_f = ws + OFF_DEPTH_F;
    float* sigma_f = ws + OFF_SIGMA_F;
    float* rgb_f   = ws + OFF_RGB_F;
    unsigned int* minmax = (unsigned int*)(ws + OFF_MINMAX);
    float* w2t = ws + OFF_W2T;
    // per-block minmax scratch: staged in rgb_f (overwritten later by fine pass)
    float* bmin = rgb_f;
    float* bmax = rgb_f + 2048;

    precompute2<<<1536, 256, 0, stream>>>(planes, w2, planes_bf, w2t);
    sample_mlp<<<NSAMP/64, 128, 0, stream>>>(planes_bf, nullptr, noise_strat, depth_c,
                                             origins, dirs, w1, b1, w2t, b2,
                                             sigma_c, rgb_c, 1);
    importance_kernel<<<NRAY/4, 256, 0, stream>>>(depth_c, sigma_c, noise_imp,
                                                  depth_f, bmin, bmax);
    reduce_minmax<<<1, 1024, 0, stream>>>(bmin, bmax, minmax);
    sample_mlp<<<NSAMP/64, 128, 0, stream>>>(planes_bf, depth_f, nullptr, nullptr,
                                             origins, dirs, w1, b1, w2t, b2,
                                             sigma_f, rgb_f, 0);
    final_march<<<NRAY/4, 256, 0, stream>>>(depth_c, sigma_c, rgb_c,
                                            depth_f, sigma_f, rgb_f, minmax, out);
}

// Round 9
// 333.452 us; speedup vs baseline: 2.3634x; 1.0386x over previous
//
#include <hip/hip_runtime.h>
#include <hip/hip_fp16.h>
#include <math.h>

// Problem constants
#define BB 2
#define RR 4096
#define NRAY (BB*RR)            // 8192
#define SC 48
#define NSAMP (NRAY*SC)         // 393216
#define CF 32
#define HID 64
#define ODIM 33                 // 1 sigma + 32 rgb
#define PRES 256
#define PLANE_HW (PRES*PRES)    // 65536
#define RAY_START 0.1f
#define RAY_END 2.0f
#define DELTA ((RAY_END-RAY_START)/(SC-1))

// workspace layout (in floats) — rgb regions now hold fp16 (half the bytes used)
#define OFF_PLANES2  ((size_t)0)
#define OFF_DEPTH_C  ((size_t)12582912)                 // 393216
#define OFF_SIGMA_C  (OFF_DEPTH_C + 393216)             // 393216
#define OFF_RGB_C    (OFF_SIGMA_C + 393216)             // fp16: 12.58M halves in 12.58M-float slot
#define OFF_DEPTH_F  (OFF_RGB_C + 12582912)             // 393216
#define OFF_SIGMA_F  (OFF_DEPTH_F + 393216)             // 393216
#define OFF_RGB_F    (OFF_SIGMA_F + 393216)             // fp16
#define OFF_MINMAX   (OFF_RGB_F + 12582912)             // 2 uints (+2 pad)
#define OFF_W2T      (OFF_MINMAX + 4)                   // 33*64 floats (w2 transposed)

typedef __attribute__((ext_vector_type(2))) float f2_t;

// packed fp32 FMA: acc.{x,y} += a.{x,y} * b.{x,y}  (one VOP3P inst = 2 FMA)
__device__ __forceinline__ void pk_fma_vv(f2_t& acc, f2_t a, f2_t b) {
    asm("v_pk_fma_f32 %0, %1, %2, %0" : "+v"(acc) : "v"(a), "v"(b));
}
// variant with the (single allowed) scalar operand: b must be wave-uniform
__device__ __forceinline__ void pk_fma_vs(f2_t& acc, f2_t a, f2_t b) {
    asm("v_pk_fma_f32 %0, %1, %2, %0" : "+v"(acc) : "v"(a), "s"(b));
}
// dword of 2 packed bf16 -> f2_t {lo, hi}
__device__ __forceinline__ f2_t bfpair(unsigned int u) {
    union { unsigned int i; float f; } lo, hi;
    lo.i = u << 16;
    hi.i = u & 0xffff0000u;
    f2_t r; r.x = lo.f; r.y = hi.f;
    return r;
}

__device__ __forceinline__ float softplusf(float x) {
    return fmaxf(x, 0.f) + __logf(1.f + __expf(-fabsf(x)));
}
__device__ __forceinline__ float sigact(float o) {
    float r = __builtin_amdgcn_rcpf(1.f + __expf(-o));
    return fmaf(1.002f, r, -0.001f);
}
__device__ __forceinline__ unsigned short f2bf(float f) {
    union { float f; unsigned int u; } v; v.f = f;
    unsigned int r = v.u + 0x7fffu + ((v.u >> 16) & 1u);   // RNE
    return (unsigned short)(r >> 16);
}
__device__ __forceinline__ unsigned int pack2(float lo, float hi) {
    return (unsigned int)f2bf(lo) | ((unsigned int)f2bf(hi) << 16);
}
// pack two floats to packed fp16 dword
__device__ __forceinline__ unsigned int pkh2(float a, float b) {
    __half2 h = __floats2half2_rn(a, b);
    union { __half2 h; unsigned int u; } cv; cv.h = h;
    return cv.u;
}
__device__ __forceinline__ float h2f(unsigned short h) {
    union { unsigned short s; __half h; } cv; cv.s = h;
    return __half2float(cv.h);
}

// ---------------------------------------------------------------------------
// Kernel 1: planes_bf[bp][y][x][c] = bf16(planes[bp][c][y][x]).
// Pure transpose+convert. Also: w2t = w2^T.
__global__ __launch_bounds__(256) void precompute2(
    const float* __restrict__ planes, const float* __restrict__ w2,
    unsigned short* __restrict__ planes_bf, float* __restrict__ w2t)
{
    if (blockIdx.x == 0 && threadIdx.x < ODIM) {
        int k = threadIdx.x;
        for (int j = 0; j < HID; ++j) w2t[k * HID + j] = w2[j * ODIM + k];
    }
    int row = blockIdx.x;
    int bp = row >> 8, y = row & 255;
    int x = threadIdx.x;
    const float* src = planes + (size_t)bp * CF * PLANE_HW + (size_t)y * PRES + x;
    unsigned short* dst = planes_bf + ((size_t)bp * PLANE_HW + (size_t)(y << 8) + x) * CF;
    #pragma unroll
    for (int q = 0; q < 4; ++q) {
        uint4 u;
        u.x = pack2(src[(size_t)(q*8+0)*PLANE_HW], src[(size_t)(q*8+1)*PLANE_HW]);
        u.y = pack2(src[(size_t)(q*8+2)*PLANE_HW], src[(size_t)(q*8+3)*PLANE_HW]);
        u.z = pack2(src[(size_t)(q*8+4)*PLANE_HW], src[(size_t)(q*8+5)*PLANE_HW]);
        u.w = pack2(src[(size_t)(q*8+6)*PLANE_HW], src[(size_t)(q*8+7)*PLANE_HW]);
        ((uint4*)dst)[q] = u;
    }
}

// ---------------------------------------------------------------------------
// Kernel 2 (R21): R20 structure; rgb output now packed fp16 (sigmoid output
// in [-.001,1.001] -> fp16 abs err <= 2^-11, negligible vs bf16 table error).
// Halves rgb write traffic here and halves final_march's dominant read.
__global__ __launch_bounds__(128, 3) void sample_mlp(
    const unsigned short* __restrict__ planes_bf,
    const float* __restrict__ depths_in,   // fine pass
    const float* __restrict__ noise,       // coarse pass
    float* __restrict__ depth_out,         // coarse pass
    const float* __restrict__ origins,
    const float* __restrict__ dirs,
    const float* __restrict__ w1,
    const float* __restrict__ b1,
    const float* __restrict__ w2t, const float* __restrict__ b2,
    float* __restrict__ sigma_out, unsigned short* __restrict__ rgb_out,
    int coarse)
{
    __shared__ __align__(16) char s_mem[8704];
    float (*s_feat)[66] = (float (*)[66])s_mem;      // [32][66] = 8448 B
    float (*s_part)[34] = (float (*)[34])s_mem;      // [64][34] = 8704 B (reused)

    int tid = threadIdx.x;

    // ---- gather phase: quad qg = tid>>2 handles samples 2qg, 2qg+1 ----
    {
        int qg = tid >> 2, sl = tid & 3;             // qg in [0,32)
        int s0 = blockIdx.x * 64 + 2 * qg;           // even -> pair never straddles a ray
        int ray = s0 / SC;
        int b = ray >> 12;

        float dep[2];
        if (coarse) {
            int sb = s0 - ray * SC;
            dep[0] = RAY_START + (float)sb * DELTA + noise[s0] * DELTA;
            dep[1] = RAY_START + (float)(sb + 1) * DELTA + noise[s0 + 1] * DELTA;
            if (sl == 0) { depth_out[s0] = dep[0]; depth_out[s0 + 1] = dep[1]; }
        } else {
            dep[0] = depths_in[s0];
            dep[1] = depths_in[s0 + 1];
        }

        float ox = origins[ray*3+0], oy = origins[ray*3+1], oz = origins[ray*3+2];
        float dx = dirs[ray*3+0],    dy = dirs[ray*3+1],    dz = dirs[ray*3+2];

        f2_t fa[2][4];
        #pragma unroll
        for (int k = 0; k < 2; ++k)
            #pragma unroll
            for (int j = 0; j < 4; ++j) fa[k][j] = (f2_t){0.f, 0.f};

        #pragma unroll
        for (int k = 0; k < 2; ++k) {
            float cx = (ox + dep[k]*dx) * 0.5f;
            float cy = (oy + dep[k]*dy) * 0.5f;
            float cz = (oz + dep[k]*dz) * 0.5f;
            #pragma unroll
            for (int p = 0; p < 3; ++p) {
                float gx = (p == 0) ? cx : (p == 1) ? cy : cz;
                float gy = (p == 0) ? cy : (p == 1) ? cz : cx;
                float x = fmaf(gx, 128.f, 127.5f);
                float y = fmaf(gy, 128.f, 127.5f);
                float x0f = floorf(x), y0f = floorf(y);
                float wx1 = x - x0f, wy1 = y - y0f;
                int x0 = (int)x0f, y0 = (int)y0f;
                const unsigned short* pb = planes_bf + (size_t)(b*3 + p) * PLANE_HW * CF;
                #pragma unroll
                for (int cyi = 0; cyi < 2; ++cyi) {
                    #pragma unroll
                    for (int cxi = 0; cxi < 2; ++cxi) {
                        int xi = x0 + cxi, yi = y0 + cyi;
                        float wgt = ((cyi ? wy1 : 1.f - wy1) * (cxi ? wx1 : 1.f - wx1)) * (1.f/3.f);
                        if (xi < 0 || xi > 255 || yi < 0 || yi > 255) wgt = 0.f;
                        int xc = min(max(xi, 0), 255), yc = min(max(yi, 0), 255);
                        const uint4* tp = (const uint4*)(pb + (size_t)((yc << 8) + xc) * CF);
                        uint4 v = tp[sl];            // quad covers the 64B texel in 1 inst
                        f2_t wp2; wp2.x = wgt; wp2.y = wgt;
                        pk_fma_vv(fa[k][0], bfpair(v.x), wp2);
                        pk_fma_vv(fa[k][1], bfpair(v.y), wp2);
                        pk_fma_vv(fa[k][2], bfpair(v.z), wp2);
                        pk_fma_vv(fa[k][3], bfpair(v.w), wp2);
                    }
                }
            }
        }

        // stash: lane owns channels [8sl, 8sl+8) for its 2 samples
        #pragma unroll
        for (int k = 0; k < 2; ++k)
            #pragma unroll
            for (int j = 0; j < 4; ++j) {
                s_feat[8*sl + 2*j    ][2*qg + k] = fa[k][j].x;
                s_feat[8*sl + 2*j + 1][2*qg + k] = fa[k][j].y;
            }
    }
    __syncthreads();

    // ---- GEMM phase: wave pair splits hidden dim (halfu wave-uniform) ----
    int lane = tid & 63;
    int halfu = __builtin_amdgcn_readfirstlane(tid >> 6);  // SGPR: scalar weight loads
    int sample = blockIdx.x * 64 + lane;

    f2_t h2[16];
    const f2_t* b1p = (const f2_t*)(b1 + halfu * 32);
    #pragma unroll
    for (int j = 0; j < 16; ++j) h2[j] = b1p[j];

    #pragma unroll
    for (int c = 0; c < CF; ++c) {
        float fc = s_feat[c][lane];
        f2_t fc2; fc2.x = fc; fc2.y = fc;
        const f2_t* wp = (const f2_t*)(w1 + c * HID + halfu * 32);
        #pragma unroll
        for (int j = 0; j < 16; ++j) pk_fma_vs(h2[j], fc2, wp[j]);
    }
    #pragma unroll
    for (int j = 0; j < 16; ++j) {
        h2[j].x = softplusf(h2[j].x);
        h2[j].y = softplusf(h2[j].y);
    }

    // partial GEMM2 over own 32 hidden channels; w2t row halves via SGPR offset.
    float o[ODIM + 1];   // pad to 34 for f2 LDS traffic
    const f2_t* wbase = (const f2_t*)(w2t + halfu * 32);
    #pragma unroll
    for (int k = 0; k < ODIM; ++k) {
        const f2_t* wp = wbase + k * (HID/2);
        f2_t acc = (f2_t){0.f, 0.f};
        #pragma unroll
        for (int j = 0; j < 16; ++j) pk_fma_vs(acc, h2[j], wp[j]);
        o[k] = acc.x + acc.y;
    }
    o[ODIM] = 0.f;

    __syncthreads();   // s_feat reads done; s_mem reused for o-partials
    if (halfu) {
        f2_t* dstp = (f2_t*)&s_part[lane][0];
        #pragma unroll
        for (int j = 0; j < 17; ++j) {
            f2_t v; v.x = o[2*j]; v.y = o[2*j+1];
            dstp[j] = v;
        }
    }
    __syncthreads();
    if (!halfu) {
        const f2_t* srcp = (const f2_t*)&s_part[lane][0];
        #pragma unroll
        for (int j = 0; j < 17; ++j) {
            f2_t v = srcp[j];
            o[2*j]   += v.x;
            o[2*j+1] += v.y;
        }
        #pragma unroll
        for (int k = 0; k < ODIM; ++k) o[k] += b2[k];

        sigma_out[sample] = o[0];       // 64 consecutive floats: coalesced

        // stage sigact'd rgb into OWN LDS row (overwrites partials; row-local)
        float* row = &s_part[lane][0];
        #pragma unroll
        for (int k = 0; k < 32; ++k) row[k] = sigact(o[1 + k]);
    }
    __syncthreads();   // rgb staged for all 64 samples

    // cooperative coalesced fp16 rgb store: 64 samples x 32 halves = 4 KB
    {
        uint4* dst = (uint4*)(rgb_out + (size_t)blockIdx.x * 64 * 32);
        #pragma unroll
        for (int i = 0; i < 2; ++i) {
            int u = i * 128 + tid;               // uint4 index 0..255 (8 halves each)
            int s = u >> 2, c0 = (u & 3) * 8;
            const float* row = &s_part[s][c0];
            uint4 v;
            v.x = pkh2(row[0], row[1]);
            v.y = pkh2(row[2], row[3]);
            v.z = pkh2(row[4], row[5]);
            v.w = pkh2(row[6], row[7]);
            dst[u] = v;                          // consecutive lanes -> consecutive 16B
        }
    }
}

// ---------------------------------------------------------------------------
// Kernel 3: importance sampling, one wave per ray; block-level minmax to
// scratch (bmin/bmax staged in the rgb_f region, overwritten by fine pass).
__global__ __launch_bounds__(256) void importance_kernel(
    const float* __restrict__ depth_c, const float* __restrict__ sigma_c,
    const float* __restrict__ noise_imp, float* __restrict__ depth_f,
    float* __restrict__ bmin, float* __restrict__ bmax)
{
    __shared__ float s_cdf[4][46];
    __shared__ float s_bins[4][47];
    __shared__ float s_red[8];
    int wave = threadIdx.x >> 6, lane = threadIdx.x & 63;
    int ray = blockIdx.x * 4 + wave;

    const float* d  = depth_c + (size_t)ray * SC;
    const float* sg = sigma_c + (size_t)ray * SC;
    float dval = (lane < SC) ? d[lane] : 0.f;
    float sval = (lane < SC) ? sg[lane] : 0.f;
    float dnext = __shfl_down(dval, 1);
    float snext = __shfl_down(sval, 1);

    float a = 0.f;
    if (lane < SC-1) {
        float dens = softplusf(0.5f * (sval + snext) - 1.f);
        a = 1.f - expf(-dens * (dnext - dval));
    }
    float f = (lane < SC-1) ? (1.f - a + 1e-10f) : 1.f;
    float incl = f;
    #pragma unroll
    for (int off = 1; off < 64; off <<= 1) {
        float t = __shfl_up(incl, off);
        if (lane >= off) incl *= t;
    }
    float T = (lane == 0) ? 1.f : __shfl_up(incl, 1);
    float w = a * T;
    float wm1 = __shfl_up(w, 1);
    float wp1 = __shfl_down(w, 1);
    float wn = 0.5f * (fmaxf(wm1, w) + fmaxf(w, wp1)) + 0.01f + 1e-5f;
    float g = (lane >= 1 && lane <= 45) ? wn : 0.f;
    float incl2 = g;
    #pragma unroll
    for (int off = 1; off < 64; off <<= 1) {
        float t = __shfl_up(incl2, off);
        if (lane >= off) incl2 += t;
    }
    float sum = __shfl(incl2, 45);
    if (lane == 0) s_cdf[wave][0] = 0.f;
    else if (lane <= 45) s_cdf[wave][lane] = incl2 / sum;
    if (lane < SC-1) s_bins[wave][lane] = 0.5f * (dval + dnext);
    __syncthreads();

    float fmn = 1e30f, fmx = -1e30f;
    if (lane < SC) {
        float u = noise_imp[(size_t)ray * SC + lane];
        int inds = 0;
        #pragma unroll
        for (int t = 0; t < 46; ++t) inds += (s_cdf[wave][t] <= u) ? 1 : 0;
        int below = max(inds - 1, 0), above = min(inds, 45);
        float cb = s_cdf[wave][below], ca = s_cdf[wave][above];
        float bb = s_bins[wave][below], ba = s_bins[wave][above];
        float den = (ca - cb < 1e-5f) ? 1.f : (ca - cb);
        float s = bb + (u - cb) / den * (ba - bb);
        depth_f[(size_t)ray * SC + lane] = s;
        fmn = s; fmx = s;
    }
    float d0 = __shfl(dval, 0), dlast = __shfl(dval, SC-1);
    fmn = fminf(fmn, d0); fmx = fmaxf(fmx, dlast);
    #pragma unroll
    for (int off = 32; off >= 1; off >>= 1) {
        fmn = fminf(fmn, __shfl_xor(fmn, off));
        fmx = fmaxf(fmx, __shfl_xor(fmx, off));
    }
    if (lane == 0) { s_red[wave] = fmn; s_red[4 + wave] = fmx; }
    __syncthreads();
    if (threadIdx.x == 0) {
        bmin[blockIdx.x] = fminf(fminf(s_red[0], s_red[1]), fminf(s_red[2], s_red[3]));
        bmax[blockIdx.x] = fmaxf(fmaxf(s_red[4], s_red[5]), fmaxf(s_red[6], s_red[7]));
    }
}

// ---------------------------------------------------------------------------
// Kernel 3b: fold 2048 per-block (min,max) pairs into minmax[0..1]. 1 block.
__global__ __launch_bounds__(1024) void reduce_minmax(
    const float* __restrict__ bmin, const float* __restrict__ bmax,
    unsigned int* __restrict__ minmax)
{
    int tid = threadIdx.x;
    float mn = fminf(bmin[tid], bmin[tid + 1024]);
    float mx = fmaxf(bmax[tid], bmax[tid + 1024]);
    #pragma unroll
    for (int off = 32; off >= 1; off >>= 1) {
        mn = fminf(mn, __shfl_xor(mn, off));
        mx = fmaxf(mx, __shfl_xor(mx, off));
    }
    __shared__ float smn[16], smx[16];
    int wv = tid >> 6;
    if ((tid & 63) == 0) { smn[wv] = mn; smx[wv] = mx; }
    __syncthreads();
    if (tid == 0) {
        float m = smn[0], M = smx[0];
        #pragma unroll
        for (int i = 1; i < 16; ++i) { m = fminf(m, smn[i]); M = fmaxf(M, smx[i]); }
        minmax[0] = __float_as_uint(m);
        minmax[1] = __float_as_uint(M);
    }
}

// ---------------------------------------------------------------------------
// Kernel 4: merge coarse+fine (stable rank sort of 96), final ray-march.
// rgb inputs now fp16 (read traffic halved: 100 -> 50 MB).
__global__ __launch_bounds__(256) void final_march(
    const float* __restrict__ depth_c, const float* __restrict__ sigma_c,
    const unsigned short* __restrict__ rgb_c,
    const float* __restrict__ depth_f, const float* __restrict__ sigma_f,
    const unsigned short* __restrict__ rgb_f,
    const unsigned int* __restrict__ minmax,
    float* __restrict__ out)
{
    __shared__ float dall[4][96];
    __shared__ float sall[4][96];
    __shared__ float dsrt[4][96];
    __shared__ float ssrt[4][96];
    __shared__ int   perm[4][96];
    __shared__ float al[4][96];

    int wid = threadIdx.x >> 6, lane = threadIdx.x & 63;
    int ray = blockIdx.x * 4 + wid;

    for (int j = lane; j < 96; j += 64) {
        float dv, sv;
        if (j < 48) { dv = depth_c[(size_t)ray*48 + j]; sv = sigma_c[(size_t)ray*48 + j]; }
        else        { dv = depth_f[(size_t)ray*48 + j-48]; sv = sigma_f[(size_t)ray*48 + j-48]; }
        dall[wid][j] = dv; sall[wid][j] = sv;
    }
    __syncthreads();
    for (int j = lane; j < 96; j += 64) {
        float dj = dall[wid][j];
        int rank = 0;
        for (int k = 0; k < 96; ++k) {
            float dk = dall[wid][k];
            rank += (dk < dj || (dk == dj && k < j)) ? 1 : 0;
        }
        dsrt[wid][rank] = dj;
        ssrt[wid][rank] = sall[wid][j];
        perm[wid][rank] = j;
    }
    __syncthreads();
    for (int i = lane; i < 95; i += 64) {
        float dlt = dsrt[wid][i+1] - dsrt[wid][i];
        float dens = softplusf(0.5f * (ssrt[wid][i] + ssrt[wid][i+1]) - 1.f);
        al[wid][i] = 1.f - expf(-dens * dlt);
    }
    __syncthreads();
    if (lane == 0) {
        float T = 1.f, wsum = 0.f, dsum = 0.f;
        for (int i = 0; i < 95; ++i) {
            float a = al[wid][i];
            float wloc = a * T;
            T *= 1.f - a + 1e-10f;
            al[wid][i] = wloc;
            wsum += wloc;
            dsum += wloc * 0.5f * (dsrt[wid][i] + dsrt[wid][i+1]);
        }
        float depth = dsum / wsum;
        if (isnan(depth)) depth = INFINITY;
        float gmn = __uint_as_float(minmax[0]);
        float gmx = __uint_as_float(minmax[1]);
        depth = fminf(fmaxf(depth, gmn), gmx);
        out[262144 + ray] = depth;
        out[270336 + ray] = wsum;
        out[278528 + ray] = T;
    }
    __syncthreads();
    int k = lane & 31, half = lane >> 5;
    int i0 = half * 48, i1 = half ? 95 : 48;
    const unsigned short* rc = rgb_c + (size_t)ray * 48 * 32;
    const unsigned short* rf = rgb_f + (size_t)ray * 48 * 32;
    float acc = 0.f;
    int j0 = perm[wid][i0];
    float cur = (j0 < 48) ? h2f(rc[j0*32 + k]) : h2f(rf[(j0-48)*32 + k]);
    for (int i = i0; i < i1; ++i) {
        int jn = perm[wid][i+1];
        float nxt = (jn < 48) ? h2f(rc[jn*32 + k]) : h2f(rf[(jn-48)*32 + k]);
        acc += al[wid][i] * (cur + nxt);
        cur = nxt;
    }
    acc *= 0.5f;
    acc += __shfl_xor(acc, 32);
    if (half == 0) out[(size_t)ray * 32 + k] = acc * 2.f - 1.f;
}

// ---------------------------------------------------------------------------
extern "C" void kernel_launch(void* const* d_in, const int* in_sizes, int n_in,
                              void* d_out, int out_size, void* d_ws, size_t ws_size,
                              hipStream_t stream) {
    const float* planes      = (const float*)d_in[0];
    const float* origins     = (const float*)d_in[1];
    const float* dirs        = (const float*)d_in[2];
    const float* w1          = (const float*)d_in[3];
    const float* b1          = (const float*)d_in[4];
    const float* w2          = (const float*)d_in[5];
    const float* b2          = (const float*)d_in[6];
    const float* noise_strat = (const float*)d_in[7];
    const float* noise_imp   = (const float*)d_in[8];
    float* out = (float*)d_out;
    float* ws  = (float*)d_ws;

    unsigned short* planes_bf = (unsigned short*)(ws + OFF_PLANES2);
    float* depth_c = ws + OFF_DEPTH_C;
    float* sigma_c = ws + OFF_SIGMA_C;
    unsigned short* rgb_c = (unsigned short*)(ws + OFF_RGB_C);
    float* depth_f = ws + OFF_DEPTH_F;
    float* sigma_f = ws + OFF_SIGMA_F;
    unsigned short* rgb_f = (unsigned short*)(ws + OFF_RGB_F);
    unsigned int* minmax = (unsigned int*)(ws + OFF_MINMAX);
    float* w2t = ws + OFF_W2T;
    // per-block minmax scratch: staged in the rgb_f region (overwritten by fine pass)
    float* bmin = (float*)rgb_f;
    float* bmax = (float*)rgb_f + 2048;

    precompute2<<<1536, 256, 0, stream>>>(planes, w2, planes_bf, w2t);
    sample_mlp<<<NSAMP/64, 128, 0, stream>>>(planes_bf, nullptr, noise_strat, depth_c,
                                             origins, dirs, w1, b1, w2t, b2,
                                             sigma_c, rgb_c, 1);
    importance_kernel<<<NRAY/4, 256, 0, stream>>>(depth_c, sigma_c, noise_imp,
                                                  depth_f, bmin, bmax);
    reduce_minmax<<<1, 1024, 0, stream>>>(bmin, bmax, minmax);
    sample_mlp<<<NSAMP/64, 128, 0, stream>>>(planes_bf, depth_f, nullptr, nullptr,
                                             origins, dirs, w1, b1, w2t, b2,
                                             sigma_f, rgb_f, 0);
    final_march<<<NRAY/4, 256, 0, stream>>>(depth_c, sigma_c, rgb_c,
                                            depth_f, sigma_f, rgb_f, minmax, out);
}

// Round 11
// 312.031 us; speedup vs baseline: 2.5257x; 1.0687x over previous
//
#include <hip/hip_runtime.h>
#include <hip/hip_fp16.h>
#include <math.h>

// Problem constants
#define BB 2
#define RR 4096
#define NRAY (BB*RR)            // 8192
#define SC 48
#define NSAMP (NRAY*SC)         // 393216
#define CF 32
#define HID 64
#define ODIM 33                 // 1 sigma + 32 rgb
#define PRES 256
#define PLANE_HW (PRES*PRES)    // 65536
#define RAY_START 0.1f
#define RAY_END 2.0f
#define DELTA ((RAY_END-RAY_START)/(SC-1))

// workspace layout (in floats) — rgb regions hold fp16 (half the bytes used).
// planes_bf (bf16) uses only the first half of its fp32-sized slot; w2f
// (MFMA fragment buffer for w2, hi/lo f16) lives in the free second half.
#define OFF_PLANES2  ((size_t)0)
#define OFF_W2F      ((size_t)6291456)                  // 3072 floats used
#define OFF_DEPTH_C  ((size_t)12582912)                 // 393216
#define OFF_SIGMA_C  (OFF_DEPTH_C + 393216)             // 393216
#define OFF_RGB_C    (OFF_SIGMA_C + 393216)             // fp16
#define OFF_DEPTH_F  (OFF_RGB_C + 12582912)             // 393216
#define OFF_SIGMA_F  (OFF_DEPTH_F + 393216)             // 393216
#define OFF_RGB_F    (OFF_SIGMA_F + 393216)             // fp16
#define OFF_MINMAX   (OFF_RGB_F + 12582912)             // 2 uints (+2 pad)

typedef __attribute__((ext_vector_type(2))) float f2_t;
typedef __attribute__((ext_vector_type(4))) float f32x4;
typedef __attribute__((ext_vector_type(8))) _Float16 f16x8;

// packed fp32 FMA: acc.{x,y} += a.{x,y} * b.{x,y}  (one VOP3P inst = 2 FMA)
__device__ __forceinline__ void pk_fma_vv(f2_t& acc, f2_t a, f2_t b) {
    asm("v_pk_fma_f32 %0, %1, %2, %0" : "+v"(acc) : "v"(a), "v"(b));
}
// variant with the (single allowed) scalar operand: b must be wave-uniform
__device__ __forceinline__ void pk_fma_vs(f2_t& acc, f2_t a, f2_t b) {
    asm("v_pk_fma_f32 %0, %1, %2, %0" : "+v"(acc) : "v"(a), "s"(b));
}
// dword of 2 packed bf16 -> f2_t {lo, hi}
__device__ __forceinline__ f2_t bfpair(unsigned int u) {
    union { unsigned int i; float f; } lo, hi;
    lo.i = u << 16;
    hi.i = u & 0xffff0000u;
    f2_t r; r.x = lo.f; r.y = hi.f;
    return r;
}

__device__ __forceinline__ float softplusf(float x) {
    return fmaxf(x, 0.f) + __logf(1.f + __expf(-fabsf(x)));
}
__device__ __forceinline__ float sigact(float o) {
    float r = __builtin_amdgcn_rcpf(1.f + __expf(-o));
    return fmaf(1.002f, r, -0.001f);
}
__device__ __forceinline__ unsigned short f2bf(float f) {
    union { float f; unsigned int u; } v; v.f = f;
    unsigned int r = v.u + 0x7fffu + ((v.u >> 16) & 1u);   // RNE
    return (unsigned short)(r >> 16);
}
__device__ __forceinline__ unsigned int pack2(float lo, float hi) {
    return (unsigned int)f2bf(lo) | ((unsigned int)f2bf(hi) << 16);
}
// pack two floats to packed fp16 dword
__device__ __forceinline__ unsigned int pkh2(float a, float b) {
    __half2 h = __floats2half2_rn(a, b);
    union { __half2 h; unsigned int u; } cv; cv.h = h;
    return cv.u;
}
__device__ __forceinline__ unsigned short f2h(float a) {
    union { _Float16 h; unsigned short s; } cv; cv.h = (_Float16)a;
    return cv.s;
}
__device__ __forceinline__ float h2f(unsigned short h) {
    union { unsigned short s; __half h; } cv; cv.s = h;
    return __half2float(cv.h);
}
// fp16 bits -> float (defined BEFORE first use this time)
__device__ __forceinline__ float h2f_dev(unsigned short h) {
    union { unsigned short s; _Float16 h; } cv; cv.s = h;
    return (float)cv.h;
}

// ---------------------------------------------------------------------------
// Kernel 1: planes_bf[bp][y][x][c] = bf16(planes[bp][c][y][x]); and build the
// MFMA fragment buffer w2f for GEMM2: B2[k=hid][n=out], f16 hi/lo split.
// Fragment layout (16x16x32): lane holds B[k0*32+(l>>4)*8+j][n0*16+(l&15)].
__global__ __launch_bounds__(256) void precompute2(
    const float* __restrict__ planes, const float* __restrict__ w2,
    unsigned short* __restrict__ planes_bf, float* __restrict__ w2f)
{
    if (blockIdx.x == 0 && threadIdx.x < 64) {
        int l = threadIdx.x;
        int l15 = l & 15, l4 = l >> 4;
        uint4* dst = (uint4*)w2f;
        for (int k0 = 0; k0 < 2; ++k0)
            for (int n0 = 0; n0 < 3; ++n0) {
                int n = n0 * 16 + l15;
                float v[8]; unsigned short hi[8], lo[8];
                #pragma unroll
                for (int j = 0; j < 8; ++j) {
                    int k = k0 * 32 + l4 * 8 + j;       // hid index
                    v[j] = (n < ODIM) ? w2[k * ODIM + n] : 0.f;
                    hi[j] = f2h(v[j]);
                    lo[j] = f2h(v[j] - h2f_dev(hi[j]));
                }
                uint4 uh, ul;
                uh.x = (unsigned int)hi[0] | ((unsigned int)hi[1] << 16);
                uh.y = (unsigned int)hi[2] | ((unsigned int)hi[3] << 16);
                uh.z = (unsigned int)hi[4] | ((unsigned int)hi[5] << 16);
                uh.w = (unsigned int)hi[6] | ((unsigned int)hi[7] << 16);
                ul.x = (unsigned int)lo[0] | ((unsigned int)lo[1] << 16);
                ul.y = (unsigned int)lo[2] | ((unsigned int)lo[3] << 16);
                ul.z = (unsigned int)lo[4] | ((unsigned int)lo[5] << 16);
                ul.w = (unsigned int)lo[6] | ((unsigned int)lo[7] << 16);
                dst[((k0 * 3 + n0) * 2 + 0) * 64 + l] = uh;
                dst[((k0 * 3 + n0) * 2 + 1) * 64 + l] = ul;
            }
    }
    int row = blockIdx.x;
    int bp = row >> 8, y = row & 255;
    int x = threadIdx.x;
    const float* src = planes + (size_t)bp * CF * PLANE_HW + (size_t)y * PRES + x;
    unsigned short* dst = planes_bf + ((size_t)bp * PLANE_HW + (size_t)(y << 8) + x) * CF;
    #pragma unroll
    for (int q = 0; q < 4; ++q) {
        uint4 u;
        u.x = pack2(src[(size_t)(q*8+0)*PLANE_HW], src[(size_t)(q*8+1)*PLANE_HW]);
        u.y = pack2(src[(size_t)(q*8+2)*PLANE_HW], src[(size_t)(q*8+3)*PLANE_HW]);
        u.z = pack2(src[(size_t)(q*8+4)*PLANE_HW], src[(size_t)(q*8+5)*PLANE_HW]);
        u.w = pack2(src[(size_t)(q*8+6)*PLANE_HW], src[(size_t)(q*8+7)*PLANE_HW]);
        ((uint4*)dst)[q] = u;
    }
}

// ---------------------------------------------------------------------------
// Kernel 2 (R23 = R22 fixed): gather + VALU GEMM1 unchanged; GEMM2 (64->33)
// moved to the idle MFMA pipe (MfmaUtil was 0.0 all session while
// VALUBusy*dur ~50us). h (fp32) -> f16 in swizzled LDS [64 samp][64 hid];
// w2 hi/lo-split fragments precomputed (w2f) so only h's f16 quantization
// adds error (<=~0.001 rgb). Per wave: 2 M x 3 N x 2 K x 2 products = 24
// MFMAs. n0-outer loop keeps peak live regs ~40 (avoids R13 spill trap).
__global__ __launch_bounds__(128, 3) void sample_mlp(
    const unsigned short* __restrict__ planes_bf,
    const float* __restrict__ depths_in,   // fine pass
    const float* __restrict__ noise,       // coarse pass
    float* __restrict__ depth_out,         // coarse pass
    const float* __restrict__ origins,
    const float* __restrict__ dirs,
    const float* __restrict__ w1,
    const float* __restrict__ b1,
    const float* __restrict__ w2f, const float* __restrict__ b2,
    float* __restrict__ sigma_out, unsigned short* __restrict__ rgb_out,
    int coarse)
{
    __shared__ __align__(16) char s_mem[16640];
    float (*s_feat)[66] = (float (*)[66])s_mem;              // [32][66] = 8448 B (region A)
    unsigned short* s_h = (unsigned short*)(s_mem + 8448);   // [64][64] f16 = 8192 B (region B)
    unsigned short* s_rgb = (unsigned short*)s_mem;          // [64][32] f16 = 4096 B (aliases A)

    int tid = threadIdx.x;

    // ---- gather phase: quad qg = tid>>2 handles samples 2qg, 2qg+1 ----
    {
        int qg = tid >> 2, sl = tid & 3;             // qg in [0,32)
        int s0 = blockIdx.x * 64 + 2 * qg;           // even -> pair never straddles a ray
        int ray = s0 / SC;
        int b = ray >> 12;

        float dep[2];
        if (coarse) {
            int sb = s0 - ray * SC;
            dep[0] = RAY_START + (float)sb * DELTA + noise[s0] * DELTA;
            dep[1] = RAY_START + (float)(sb + 1) * DELTA + noise[s0 + 1] * DELTA;
            if (sl == 0) { depth_out[s0] = dep[0]; depth_out[s0 + 1] = dep[1]; }
        } else {
            dep[0] = depths_in[s0];
            dep[1] = depths_in[s0 + 1];
        }

        float ox = origins[ray*3+0], oy = origins[ray*3+1], oz = origins[ray*3+2];
        float dx = dirs[ray*3+0],    dy = dirs[ray*3+1],    dz = dirs[ray*3+2];

        f2_t fa[2][4];
        #pragma unroll
        for (int k = 0; k < 2; ++k)
            #pragma unroll
            for (int j = 0; j < 4; ++j) fa[k][j] = (f2_t){0.f, 0.f};

        #pragma unroll
        for (int k = 0; k < 2; ++k) {
            float cx = (ox + dep[k]*dx) * 0.5f;
            float cy = (oy + dep[k]*dy) * 0.5f;
            float cz = (oz + dep[k]*dz) * 0.5f;
            #pragma unroll
            for (int p = 0; p < 3; ++p) {
                float gx = (p == 0) ? cx : (p == 1) ? cy : cz;
                float gy = (p == 0) ? cy : (p == 1) ? cz : cx;
                float x = fmaf(gx, 128.f, 127.5f);
                float y = fmaf(gy, 128.f, 127.5f);
                float x0f = floorf(x), y0f = floorf(y);
                float wx1 = x - x0f, wy1 = y - y0f;
                int x0 = (int)x0f, y0 = (int)y0f;
                const unsigned short* pb = planes_bf + (size_t)(b*3 + p) * PLANE_HW * CF;
                #pragma unroll
                for (int cyi = 0; cyi < 2; ++cyi) {
                    #pragma unroll
                    for (int cxi = 0; cxi < 2; ++cxi) {
                        int xi = x0 + cxi, yi = y0 + cyi;
                        float wgt = ((cyi ? wy1 : 1.f - wy1) * (cxi ? wx1 : 1.f - wx1)) * (1.f/3.f);
                        if (xi < 0 || xi > 255 || yi < 0 || yi > 255) wgt = 0.f;
                        int xc = min(max(xi, 0), 255), yc = min(max(yi, 0), 255);
                        const uint4* tp = (const uint4*)(pb + (size_t)((yc << 8) + xc) * CF);
                        uint4 v = tp[sl];            // quad covers the 64B texel in 1 inst
                        f2_t wp2; wp2.x = wgt; wp2.y = wgt;
                        pk_fma_vv(fa[k][0], bfpair(v.x), wp2);
                        pk_fma_vv(fa[k][1], bfpair(v.y), wp2);
                        pk_fma_vv(fa[k][2], bfpair(v.z), wp2);
                        pk_fma_vv(fa[k][3], bfpair(v.w), wp2);
                    }
                }
            }
        }

        // stash: lane owns channels [8sl, 8sl+8) for its 2 samples
        #pragma unroll
        for (int k = 0; k < 2; ++k)
            #pragma unroll
            for (int j = 0; j < 4; ++j) {
                s_feat[8*sl + 2*j    ][2*qg + k] = fa[k][j].x;
                s_feat[8*sl + 2*j + 1][2*qg + k] = fa[k][j].y;
            }
    }
    __syncthreads();

    // ---- GEMM1 (VALU, unchanged): wave pair splits hidden dim ----
    int lane = tid & 63;
    int halfu = __builtin_amdgcn_readfirstlane(tid >> 6);  // SGPR: scalar weight loads

    f2_t h2[16];
    const f2_t* b1p = (const f2_t*)(b1 + halfu * 32);
    #pragma unroll
    for (int j = 0; j < 16; ++j) h2[j] = b1p[j];

    #pragma unroll
    for (int c = 0; c < CF; ++c) {
        float fc = s_feat[c][lane];
        f2_t fc2; fc2.x = fc; fc2.y = fc;
        const f2_t* wp = (const f2_t*)(w1 + c * HID + halfu * 32);
        #pragma unroll
        for (int j = 0; j < 16; ++j) pk_fma_vs(h2[j], fc2, wp[j]);
    }
    #pragma unroll
    for (int j = 0; j < 16; ++j) {
        h2[j].x = softplusf(h2[j].x);
        h2[j].y = softplusf(h2[j].y);
    }

    // ---- h -> LDS f16, swizzled rows (byte_blk ^= row&7) ----
    {
        char* rowp = (char*)s_h + lane * 128;
        #pragma unroll
        for (int q = 0; q < 4; ++q) {
            uint4 u;
            u.x = pkh2(h2[4*q+0].x, h2[4*q+0].y);
            u.y = pkh2(h2[4*q+1].x, h2[4*q+1].y);
            u.z = pkh2(h2[4*q+2].x, h2[4*q+2].y);
            u.w = pkh2(h2[4*q+3].x, h2[4*q+3].y);
            int blk = (halfu * 4 + q) ^ (lane & 7);
            *(uint4*)(rowp + blk * 16) = u;
        }
    }
    __syncthreads();   // h complete (both waves' hid halves); s_feat dead

    // ---- GEMM2 via MFMA 16x16x32 f16: wave halfu owns samples [32h,32h+32) ----
    {
        int l15 = lane & 15, l4 = lane >> 4;
        const uint4* w2f4 = (const uint4*)w2f;
        int gbase = blockIdx.x * 64;

        #pragma unroll
        for (int n0 = 0; n0 < 3; ++n0) {
            f32x4 acc0 = {0.f, 0.f, 0.f, 0.f};
            f32x4 acc1 = {0.f, 0.f, 0.f, 0.f};
            #pragma unroll
            for (int k0 = 0; k0 < 2; ++k0) {
                union { uint4 u; f16x8 h; } Bh, Bl;
                Bh.u = w2f4[((k0 * 3 + n0) * 2 + 0) * 64 + lane];
                Bl.u = w2f4[((k0 * 3 + n0) * 2 + 1) * 64 + lane];
                #pragma unroll
                for (int m = 0; m < 2; ++m) {
                    int rowi = halfu * 32 + m * 16 + l15;
                    int blk = (k0 * 4 + l4) ^ (rowi & 7);
                    union { uint4 u; f16x8 h; } A;
                    A.u = *(const uint4*)((const char*)s_h + rowi * 128 + blk * 16);
                    if (m == 0) {
                        acc0 = __builtin_amdgcn_mfma_f32_16x16x32_f16(A.h, Bh.h, acc0, 0, 0, 0);
                        acc0 = __builtin_amdgcn_mfma_f32_16x16x32_f16(A.h, Bl.h, acc0, 0, 0, 0);
                    } else {
                        acc1 = __builtin_amdgcn_mfma_f32_16x16x32_f16(A.h, Bh.h, acc1, 0, 0, 0);
                        acc1 = __builtin_amdgcn_mfma_f32_16x16x32_f16(A.h, Bl.h, acc1, 0, 0, 0);
                    }
                }
            }
            // epilogue for this n0: D layout col=l&15 (out ch), row=(l>>4)*4+reg (sample)
            int nn = n0 * 16 + l15;
            float bv = (nn < ODIM) ? b2[nn] : 0.f;
            #pragma unroll
            for (int m = 0; m < 2; ++m) {
                f32x4 acc = m ? acc1 : acc0;
                #pragma unroll
                for (int r = 0; r < 4; ++r) {
                    float val = acc[r] + bv;
                    int sl_ = halfu * 32 + m * 16 + l4 * 4 + r;
                    if (n0 == 0 && l15 == 0) sigma_out[gbase + sl_] = val;
                    if (nn >= 1 && nn < ODIM) s_rgb[sl_ * 32 + (nn - 1)] = f2h(sigact(val));
                }
            }
        }
    }
    __syncthreads();   // rgb staged for all 64 samples

    // cooperative coalesced fp16 rgb store: 64 samples x 32 halves = 4 KB
    {
        uint4* dst = (uint4*)(rgb_out + (size_t)blockIdx.x * 64 * 32);
        const uint4* src = (const uint4*)s_rgb;
        #pragma unroll
        for (int i = 0; i < 2; ++i) {
            int u = i * 128 + tid;
            dst[u] = src[u];
        }
    }
}

// ---------------------------------------------------------------------------
// Kernel 3: importance sampling, one wave per ray; block-level minmax to
// scratch (bmin/bmax staged in the rgb_f region, overwritten by fine pass).
__global__ __launch_bounds__(256) void importance_kernel(
    const float* __restrict__ depth_c, const float* __restrict__ sigma_c,
    const float* __restrict__ noise_imp, float* __restrict__ depth_f,
    float* __restrict__ bmin, float* __restrict__ bmax)
{
    __shared__ float s_cdf[4][46];
    __shared__ float s_bins[4][47];
    __shared__ float s_red[8];
    int wave = threadIdx.x >> 6, lane = threadIdx.x & 63;
    int ray = blockIdx.x * 4 + wave;

    const float* d  = depth_c + (size_t)ray * SC;
    const float* sg = sigma_c + (size_t)ray * SC;
    float dval = (lane < SC) ? d[lane] : 0.f;
    float sval = (lane < SC) ? sg[lane] : 0.f;
    float dnext = __shfl_down(dval, 1);
    float snext = __shfl_down(sval, 1);

    float a = 0.f;
    if (lane < SC-1) {
        float dens = softplusf(0.5f * (sval + snext) - 1.f);
        a = 1.f - expf(-dens * (dnext - dval));
    }
    float f = (lane < SC-1) ? (1.f - a + 1e-10f) : 1.f;
    float incl = f;
    #pragma unroll
    for (int off = 1; off < 64; off <<= 1) {
        float t = __shfl_up(incl, off);
        if (lane >= off) incl *= t;
    }
    float T = (lane == 0) ? 1.f : __shfl_up(incl, 1);
    float w = a * T;
    float wm1 = __shfl_up(w, 1);
    float wp1 = __shfl_down(w, 1);
    float wn = 0.5f * (fmaxf(wm1, w) + fmaxf(w, wp1)) + 0.01f + 1e-5f;
    float g = (lane >= 1 && lane <= 45) ? wn : 0.f;
    float incl2 = g;
    #pragma unroll
    for (int off = 1; off < 64; off <<= 1) {
        float t = __shfl_up(incl2, off);
        if (lane >= off) incl2 += t;
    }
    float sum = __shfl(incl2, 45);
    if (lane == 0) s_cdf[wave][0] = 0.f;
    else if (lane <= 45) s_cdf[wave][lane] = incl2 / sum;
    if (lane < SC-1) s_bins[wave][lane] = 0.5f * (dval + dnext);
    __syncthreads();

    float fmn = 1e30f, fmx = -1e30f;
    if (lane < SC) {
        float u = noise_imp[(size_t)ray * SC + lane];
        int inds = 0;
        #pragma unroll
        for (int t = 0; t < 46; ++t) inds += (s_cdf[wave][t] <= u) ? 1 : 0;
        int below = max(inds - 1, 0), above = min(inds, 45);
        float cb = s_cdf[wave][below], ca = s_cdf[wave][above];
        float bb = s_bins[wave][below], ba = s_bins[wave][above];
        float den = (ca - cb < 1e-5f) ? 1.f : (ca - cb);
        float s = bb + (u - cb) / den * (ba - bb);
        depth_f[(size_t)ray * SC + lane] = s;
        fmn = s; fmx = s;
    }
    float d0 = __shfl(dval, 0), dlast = __shfl(dval, SC-1);
    fmn = fminf(fmn, d0); fmx = fmaxf(fmx, dlast);
    #pragma unroll
    for (int off = 32; off >= 1; off >>= 1) {
        fmn = fminf(fmn, __shfl_xor(fmn, off));
        fmx = fmaxf(fmx, __shfl_xor(fmx, off));
    }
    if (lane == 0) { s_red[wave] = fmn; s_red[4 + wave] = fmx; }
    __syncthreads();
    if (threadIdx.x == 0) {
        bmin[blockIdx.x] = fminf(fminf(s_red[0], s_red[1]), fminf(s_red[2], s_red[3]));
        bmax[blockIdx.x] = fmaxf(fmaxf(s_red[4], s_red[5]), fmaxf(s_red[6], s_red[7]));
    }
}

// ---------------------------------------------------------------------------
// Kernel 3b: fold 2048 per-block (min,max) pairs into minmax[0..1]. 1 block.
__global__ __launch_bounds__(1024) void reduce_minmax(
    const float* __restrict__ bmin, const float* __restrict__ bmax,
    unsigned int* __restrict__ minmax)
{
    int tid = threadIdx.x;
    float mn = fminf(bmin[tid], bmin[tid + 1024]);
    float mx = fmaxf(bmax[tid], bmax[tid + 1024]);
    #pragma unroll
    for (int off = 32; off >= 1; off >>= 1) {
        mn = fminf(mn, __shfl_xor(mn, off));
        mx = fmaxf(mx, __shfl_xor(mx, off));
    }
    __shared__ float smn[16], smx[16];
    int wv = tid >> 6;
    if ((tid & 63) == 0) { smn[wv] = mn; smx[wv] = mx; }
    __syncthreads();
    if (tid == 0) {
        float m = smn[0], M = smx[0];
        #pragma unroll
        for (int i = 1; i < 16; ++i) { m = fminf(m, smn[i]); M = fmaxf(M, smx[i]); }
        minmax[0] = __float_as_uint(m);
        minmax[1] = __float_as_uint(M);
    }
}

// ---------------------------------------------------------------------------
// Kernel 4: merge coarse+fine (stable rank sort of 96), final ray-march.
// rgb inputs fp16.
__global__ __launch_bounds__(256) void final_march(
    const float* __restrict__ depth_c, const float* __restrict__ sigma_c,
    const unsigned short* __restrict__ rgb_c,
    const float* __restrict__ depth_f, const float* __restrict__ sigma_f,
    const unsigned short* __restrict__ rgb_f,
    const unsigned int* __restrict__ minmax,
    float* __restrict__ out)
{
    __shared__ float dall[4][96];
    __shared__ float sall[4][96];
    __shared__ float dsrt[4][96];
    __shared__ float ssrt[4][96];
    __shared__ int   perm[4][96];
    __shared__ float al[4][96];

    int wid = threadIdx.x >> 6, lane = threadIdx.x & 63;
    int ray = blockIdx.x * 4 + wid;

    for (int j = lane; j < 96; j += 64) {
        float dv, sv;
        if (j < 48) { dv = depth_c[(size_t)ray*48 + j]; sv = sigma_c[(size_t)ray*48 + j]; }
        else        { dv = depth_f[(size_t)ray*48 + j-48]; sv = sigma_f[(size_t)ray*48 + j-48]; }
        dall[wid][j] = dv; sall[wid][j] = sv;
    }
    __syncthreads();
    for (int j = lane; j < 96; j += 64) {
        float dj = dall[wid][j];
        int rank = 0;
        for (int k = 0; k < 96; ++k) {
            float dk = dall[wid][k];
            rank += (dk < dj || (dk == dj && k < j)) ? 1 : 0;
        }
        dsrt[wid][rank] = dj;
        ssrt[wid][rank] = sall[wid][j];
        perm[wid][rank] = j;
    }
    __syncthreads();
    for (int i = lane; i < 95; i += 64) {
        float dlt = dsrt[wid][i+1] - dsrt[wid][i];
        float dens = softplusf(0.5f * (ssrt[wid][i] + ssrt[wid][i+1]) - 1.f);
        al[wid][i] = 1.f - expf(-dens * dlt);
    }
    __syncthreads();
    if (lane == 0) {
        float T = 1.f, wsum = 0.f, dsum = 0.f;
        for (int i = 0; i < 95; ++i) {
            float a = al[wid][i];
            float wloc = a * T;
            T *= 1.f - a + 1e-10f;
            al[wid][i] = wloc;
            wsum += wloc;
            dsum += wloc * 0.5f * (dsrt[wid][i] + dsrt[wid][i+1]);
        }
        float depth = dsum / wsum;
        if (isnan(depth)) depth = INFINITY;
        float gmn = __uint_as_float(minmax[0]);
        float gmx = __uint_as_float(minmax[1]);
        depth = fminf(fmaxf(depth, gmn), gmx);
        out[262144 + ray] = depth;
        out[270336 + ray] = wsum;
        out[278528 + ray] = T;
    }
    __syncthreads();
    int k = lane & 31, half = lane >> 5;
    int i0 = half * 48, i1 = half ? 95 : 48;
    const unsigned short* rc = rgb_c + (size_t)ray * 48 * 32;
    const unsigned short* rf = rgb_f + (size_t)ray * 48 * 32;
    float acc = 0.f;
    int j0 = perm[wid][i0];
    float cur = (j0 < 48) ? h2f(rc[j0*32 + k]) : h2f(rf[(j0-48)*32 + k]);
    for (int i = i0; i < i1; ++i) {
        int jn = perm[wid][i+1];
        float nxt = (jn < 48) ? h2f(rc[jn*32 + k]) : h2f(rf[(jn-48)*32 + k]);
        acc += al[wid][i] * (cur + nxt);
        cur = nxt;
    }
    acc *= 0.5f;
    acc += __shfl_xor(acc, 32);
    if (half == 0) out[(size_t)ray * 32 + k] = acc * 2.f - 1.f;
}

// ---------------------------------------------------------------------------
extern "C" void kernel_launch(void* const* d_in, const int* in_sizes, int n_in,
                              void* d_out, int out_size, void* d_ws, size_t ws_size,
                              hipStream_t stream) {
    const float* planes      = (const float*)d_in[0];
    const float* origins     = (const float*)d_in[1];
    const float* dirs        = (const float*)d_in[2];
    const float* w1          = (const float*)d_in[3];
    const float* b1          = (const float*)d_in[4];
    const float* w2          = (const float*)d_in[5];
    const float* b2          = (const float*)d_in[6];
    const float* noise_strat = (const float*)d_in[7];
    const float* noise_imp   = (const float*)d_in[8];
    float* out = (float*)d_out;
    float* ws  = (float*)d_ws;

    unsigned short* planes_bf = (unsigned short*)(ws + OFF_PLANES2);
    float* w2f = ws + OFF_W2F;
    float* depth_c = ws + OFF_DEPTH_C;
    float* sigma_c = ws + OFF_SIGMA_C;
    unsigned short* rgb_c = (unsigned short*)(ws + OFF_RGB_C);
    float* depth_f = ws + OFF_DEPTH_F;
    float* sigma_f = ws + OFF_SIGMA_F;
    unsigned short* rgb_f = (unsigned short*)(ws + OFF_RGB_F);
    unsigned int* minmax = (unsigned int*)(ws + OFF_MINMAX);
    // per-block minmax scratch: staged in the rgb_f region (overwritten by fine pass)
    float* bmin = (float*)rgb_f;
    float* bmax = (float*)rgb_f + 2048;

    precompute2<<<1536, 256, 0, stream>>>(planes, w2, planes_bf, w2f);
    sample_mlp<<<NSAMP/64, 128, 0, stream>>>(planes_bf, nullptr, noise_strat, depth_c,
                                             origins, dirs, w1, b1, w2f, b2,
                                             sigma_c, rgb_c, 1);
    importance_kernel<<<NRAY/4, 256, 0, stream>>>(depth_c, sigma_c, noise_imp,
                                                  depth_f, bmin, bmax);
    reduce_minmax<<<1, 1024, 0, stream>>>(bmin, bmax, minmax);
    sample_mlp<<<NSAMP/64, 128, 0, stream>>>(planes_bf, depth_f, nullptr, nullptr,
                                             origins, dirs, w1, b1, w2f, b2,
                                             sigma_f, rgb_f, 0);
    final_march<<<NRAY/4, 256, 0, stream>>>(depth_c, sigma_c, rgb_c,
                                            depth_f, sigma_f, rgb_f, minmax, out);
}

// Round 12
// 267.596 us; speedup vs baseline: 2.9451x; 1.1661x over previous
//
#include <hip/hip_runtime.h>
#include <hip/hip_fp16.h>
#include <math.h>

// Problem constants
#define BB 2
#define RR 4096
#define NRAY (BB*RR)            // 8192
#define SC 48
#define NSAMP (NRAY*SC)         // 393216
#define CF 32
#define HID 64
#define ODIM 33                 // 1 sigma + 32 rgb
#define PRES 256
#define PLANE_HW (PRES*PRES)    // 65536
#define RAY_START 0.1f
#define RAY_END 2.0f
#define DELTA ((RAY_END-RAY_START)/(SC-1))

// workspace layout (in floats) — rgb regions hold fp16 (half the bytes used).
// planes_bf (bf16) uses only the first half of its fp32-sized slot; w2f/w1f
// (MFMA fragment buffers, hi/lo f16) live in the free second half.
#define OFF_PLANES2  ((size_t)0)
#define OFF_W2F      ((size_t)6291456)                  // 3072 floats
#define OFF_W1F      (OFF_W2F + 3072)                   // 2048 floats
#define OFF_DEPTH_C  ((size_t)12582912)                 // 393216
#define OFF_SIGMA_C  (OFF_DEPTH_C + 393216)             // 393216
#define OFF_RGB_C    (OFF_SIGMA_C + 393216)             // fp16
#define OFF_DEPTH_F  (OFF_RGB_C + 12582912)             // 393216
#define OFF_SIGMA_F  (OFF_DEPTH_F + 393216)             // 393216
#define OFF_RGB_F    (OFF_SIGMA_F + 393216)             // fp16
#define OFF_MINMAX   (OFF_RGB_F + 12582912)             // 2 uints (+2 pad)

typedef __attribute__((ext_vector_type(2))) float f2_t;
typedef __attribute__((ext_vector_type(4))) float f32x4;
typedef __attribute__((ext_vector_type(8))) _Float16 f16x8;

// packed fp32 FMA: acc.{x,y} += a.{x,y} * b.{x,y}  (one VOP3P inst = 2 FMA)
__device__ __forceinline__ void pk_fma_vv(f2_t& acc, f2_t a, f2_t b) {
    asm("v_pk_fma_f32 %0, %1, %2, %0" : "+v"(acc) : "v"(a), "v"(b));
}
// dword of 2 packed bf16 -> f2_t {lo, hi}
__device__ __forceinline__ f2_t bfpair(unsigned int u) {
    union { unsigned int i; float f; } lo, hi;
    lo.i = u << 16;
    hi.i = u & 0xffff0000u;
    f2_t r; r.x = lo.f; r.y = hi.f;
    return r;
}

__device__ __forceinline__ float softplusf(float x) {
    return fmaxf(x, 0.f) + __logf(1.f + __expf(-fabsf(x)));
}
__device__ __forceinline__ float sigact(float o) {
    float r = __builtin_amdgcn_rcpf(1.f + __expf(-o));
    return fmaf(1.002f, r, -0.001f);
}
__device__ __forceinline__ unsigned short f2bf(float f) {
    union { float f; unsigned int u; } v; v.f = f;
    unsigned int r = v.u + 0x7fffu + ((v.u >> 16) & 1u);   // RNE
    return (unsigned short)(r >> 16);
}
__device__ __forceinline__ unsigned int pack2(float lo, float hi) {
    return (unsigned int)f2bf(lo) | ((unsigned int)f2bf(hi) << 16);
}
// pack two floats to packed fp16 dword
__device__ __forceinline__ unsigned int pkh2(float a, float b) {
    __half2 h = __floats2half2_rn(a, b);
    union { __half2 h; unsigned int u; } cv; cv.h = h;
    return cv.u;
}
__device__ __forceinline__ unsigned short f2h(float a) {
    union { _Float16 h; unsigned short s; } cv; cv.h = (_Float16)a;
    return cv.s;
}
__device__ __forceinline__ float h2f(unsigned short h) {
    union { unsigned short s; __half h; } cv; cv.s = h;
    return __half2float(cv.h);
}
// fp16 bits -> float (defined before first use)
__device__ __forceinline__ float h2f_dev(unsigned short h) {
    union { unsigned short s; _Float16 h; } cv; cv.s = h;
    return (float)cv.h;
}

// ---------------------------------------------------------------------------
// Kernel 1: planes_bf[bp][y][x][c] = bf16(planes[bp][c][y][x]); plus MFMA
// fragment buffers: w2f (GEMM2 B, K=64: 2 k0 x 3 n0 x hi/lo) and w1f
// (GEMM1 B, K=32: 4 n0 x hi/lo). Fragment: lane l holds B[k-chunk l>>4, j]
// [n0*16 + (l&15)], k ascending within the 16B.
__global__ __launch_bounds__(256) void precompute2(
    const float* __restrict__ planes, const float* __restrict__ w1,
    const float* __restrict__ w2,
    unsigned short* __restrict__ planes_bf, float* __restrict__ w2f,
    float* __restrict__ w1f)
{
    if (blockIdx.x == 0 && threadIdx.x < 64) {
        int l = threadIdx.x;
        int l15 = l & 15, l4 = l >> 4;
        uint4* dst = (uint4*)w2f;
        for (int k0 = 0; k0 < 2; ++k0)
            for (int n0 = 0; n0 < 3; ++n0) {
                int n = n0 * 16 + l15;
                float v[8]; unsigned short hi[8], lo[8];
                #pragma unroll
                for (int j = 0; j < 8; ++j) {
                    int k = k0 * 32 + l4 * 8 + j;       // hid index
                    v[j] = (n < ODIM) ? w2[k * ODIM + n] : 0.f;
                    hi[j] = f2h(v[j]);
                    lo[j] = f2h(v[j] - h2f_dev(hi[j]));
                }
                uint4 uh, ul;
                uh.x = (unsigned int)hi[0] | ((unsigned int)hi[1] << 16);
                uh.y = (unsigned int)hi[2] | ((unsigned int)hi[3] << 16);
                uh.z = (unsigned int)hi[4] | ((unsigned int)hi[5] << 16);
                uh.w = (unsigned int)hi[6] | ((unsigned int)hi[7] << 16);
                ul.x = (unsigned int)lo[0] | ((unsigned int)lo[1] << 16);
                ul.y = (unsigned int)lo[2] | ((unsigned int)lo[3] << 16);
                ul.z = (unsigned int)lo[4] | ((unsigned int)lo[5] << 16);
                ul.w = (unsigned int)lo[6] | ((unsigned int)lo[7] << 16);
                dst[((k0 * 3 + n0) * 2 + 0) * 64 + l] = uh;
                dst[((k0 * 3 + n0) * 2 + 1) * 64 + l] = ul;
            }
    }
    if (blockIdx.x == 1 && threadIdx.x < 64) {
        int l = threadIdx.x;
        int l15 = l & 15, l4 = l >> 4;
        uint4* dst = (uint4*)w1f;
        for (int n0 = 0; n0 < 4; ++n0) {
            int n = n0 * 16 + l15;
            float v[8]; unsigned short hi[8], lo[8];
            #pragma unroll
            for (int j = 0; j < 8; ++j) {
                int k = l4 * 8 + j;                     // feature index (K=32)
                v[j] = w1[k * HID + n];
                hi[j] = f2h(v[j]);
                lo[j] = f2h(v[j] - h2f_dev(hi[j]));
            }
            uint4 uh, ul;
            uh.x = (unsigned int)hi[0] | ((unsigned int)hi[1] << 16);
            uh.y = (unsigned int)hi[2] | ((unsigned int)hi[3] << 16);
            uh.z = (unsigned int)hi[4] | ((unsigned int)hi[5] << 16);
            uh.w = (unsigned int)hi[6] | ((unsigned int)hi[7] << 16);
            ul.x = (unsigned int)lo[0] | ((unsigned int)lo[1] << 16);
            ul.y = (unsigned int)lo[2] | ((unsigned int)lo[3] << 16);
            ul.z = (unsigned int)lo[4] | ((unsigned int)lo[5] << 16);
            ul.w = (unsigned int)lo[6] | ((unsigned int)lo[7] << 16);
            dst[(n0 * 2 + 0) * 64 + l] = uh;
            dst[(n0 * 2 + 1) * 64 + l] = ul;
        }
    }
    int row = blockIdx.x;
    int bp = row >> 8, y = row & 255;
    int x = threadIdx.x;
    const float* src = planes + (size_t)bp * CF * PLANE_HW + (size_t)y * PRES + x;
    unsigned short* dst = planes_bf + ((size_t)bp * PLANE_HW + (size_t)(y << 8) + x) * CF;
    #pragma unroll
    for (int q = 0; q < 4; ++q) {
        uint4 u;
        u.x = pack2(src[(size_t)(q*8+0)*PLANE_HW], src[(size_t)(q*8+1)*PLANE_HW]);
        u.y = pack2(src[(size_t)(q*8+2)*PLANE_HW], src[(size_t)(q*8+3)*PLANE_HW]);
        u.z = pack2(src[(size_t)(q*8+4)*PLANE_HW], src[(size_t)(q*8+5)*PLANE_HW]);
        u.w = pack2(src[(size_t)(q*8+6)*PLANE_HW], src[(size_t)(q*8+7)*PLANE_HW]);
        ((uint4*)dst)[q] = u;
    }
}

// ---------------------------------------------------------------------------
// Kernel 2 (R24): gather unchanged; BOTH GEMMs now on the MFMA pipe (R23
// validated the fragment recipe end-to-end: absmax unchanged). GEMM1: A from
// fp32 s_feat (8 scalar reads + f16 pack; conflict-free banks), B from w1f,
// epilogue = b1+softplus on D regs, h scatter-written to s_h with the SAME
// ^(sample&7) 16B-block swizzle GEMM2's A-read uses. GEMM2 unchanged.
__global__ __launch_bounds__(128, 3) void sample_mlp(
    const unsigned short* __restrict__ planes_bf,
    const float* __restrict__ depths_in,   // fine pass
    const float* __restrict__ noise,       // coarse pass
    float* __restrict__ depth_out,         // coarse pass
    const float* __restrict__ origins,
    const float* __restrict__ dirs,
    const float* __restrict__ w1f,
    const float* __restrict__ b1,
    const float* __restrict__ w2f, const float* __restrict__ b2,
    float* __restrict__ sigma_out, unsigned short* __restrict__ rgb_out,
    int coarse)
{
    __shared__ __align__(16) char s_mem[16640];
    float (*s_feat)[66] = (float (*)[66])s_mem;              // [32][66] = 8448 B (region A)
    unsigned short* s_h = (unsigned short*)(s_mem + 8448);   // [64][64] f16 = 8192 B (region B)
    unsigned short* s_rgb = (unsigned short*)s_mem;          // [64][32] f16 = 4096 B (aliases A)

    int tid = threadIdx.x;

    // ---- gather phase: quad qg = tid>>2 handles samples 2qg, 2qg+1 ----
    {
        int qg = tid >> 2, sl = tid & 3;             // qg in [0,32)
        int s0 = blockIdx.x * 64 + 2 * qg;           // even -> pair never straddles a ray
        int ray = s0 / SC;
        int b = ray >> 12;

        float dep[2];
        if (coarse) {
            int sb = s0 - ray * SC;
            dep[0] = RAY_START + (float)sb * DELTA + noise[s0] * DELTA;
            dep[1] = RAY_START + (float)(sb + 1) * DELTA + noise[s0 + 1] * DELTA;
            if (sl == 0) { depth_out[s0] = dep[0]; depth_out[s0 + 1] = dep[1]; }
        } else {
            dep[0] = depths_in[s0];
            dep[1] = depths_in[s0 + 1];
        }

        float ox = origins[ray*3+0], oy = origins[ray*3+1], oz = origins[ray*3+2];
        float dx = dirs[ray*3+0],    dy = dirs[ray*3+1],    dz = dirs[ray*3+2];

        f2_t fa[2][4];
        #pragma unroll
        for (int k = 0; k < 2; ++k)
            #pragma unroll
            for (int j = 0; j < 4; ++j) fa[k][j] = (f2_t){0.f, 0.f};

        #pragma unroll
        for (int k = 0; k < 2; ++k) {
            float cx = (ox + dep[k]*dx) * 0.5f;
            float cy = (oy + dep[k]*dy) * 0.5f;
            float cz = (oz + dep[k]*dz) * 0.5f;
            #pragma unroll
            for (int p = 0; p < 3; ++p) {
                float gx = (p == 0) ? cx : (p == 1) ? cy : cz;
                float gy = (p == 0) ? cy : (p == 1) ? cz : cx;
                float x = fmaf(gx, 128.f, 127.5f);
                float y = fmaf(gy, 128.f, 127.5f);
                float x0f = floorf(x), y0f = floorf(y);
                float wx1 = x - x0f, wy1 = y - y0f;
                int x0 = (int)x0f, y0 = (int)y0f;
                const unsigned short* pb = planes_bf + (size_t)(b*3 + p) * PLANE_HW * CF;
                #pragma unroll
                for (int cyi = 0; cyi < 2; ++cyi) {
                    #pragma unroll
                    for (int cxi = 0; cxi < 2; ++cxi) {
                        int xi = x0 + cxi, yi = y0 + cyi;
                        float wgt = ((cyi ? wy1 : 1.f - wy1) * (cxi ? wx1 : 1.f - wx1)) * (1.f/3.f);
                        if (xi < 0 || xi > 255 || yi < 0 || yi > 255) wgt = 0.f;
                        int xc = min(max(xi, 0), 255), yc = min(max(yi, 0), 255);
                        const uint4* tp = (const uint4*)(pb + (size_t)((yc << 8) + xc) * CF);
                        uint4 v = tp[sl];            // quad covers the 64B texel in 1 inst
                        f2_t wp2; wp2.x = wgt; wp2.y = wgt;
                        pk_fma_vv(fa[k][0], bfpair(v.x), wp2);
                        pk_fma_vv(fa[k][1], bfpair(v.y), wp2);
                        pk_fma_vv(fa[k][2], bfpair(v.z), wp2);
                        pk_fma_vv(fa[k][3], bfpair(v.w), wp2);
                    }
                }
            }
        }

        // stash: lane owns channels [8sl, 8sl+8) for its 2 samples
        #pragma unroll
        for (int k = 0; k < 2; ++k)
            #pragma unroll
            for (int j = 0; j < 4; ++j) {
                s_feat[8*sl + 2*j    ][2*qg + k] = fa[k][j].x;
                s_feat[8*sl + 2*j + 1][2*qg + k] = fa[k][j].y;
            }
    }
    __syncthreads();

    int lane = tid & 63;
    int halfu = __builtin_amdgcn_readfirstlane(tid >> 6);  // wave: samples [32h,32h+32)
    int l15 = lane & 15, l4 = lane >> 4;

    // ---- GEMM1 via MFMA: A from s_feat (fp32->f16), B from w1f ----
    {
        union { uint4 u; f16x8 h; } A0, A1;
        {
            int row0 = halfu * 32 + l15;       // m=0 tile sample row
            int row1 = row0 + 16;              // m=1 tile
            float f0[8], f1[8];
            #pragma unroll
            for (int j = 0; j < 8; ++j) {
                f0[j] = s_feat[l4*8 + j][row0];
                f1[j] = s_feat[l4*8 + j][row1];
            }
            A0.u.x = pkh2(f0[0], f0[1]); A0.u.y = pkh2(f0[2], f0[3]);
            A0.u.z = pkh2(f0[4], f0[5]); A0.u.w = pkh2(f0[6], f0[7]);
            A1.u.x = pkh2(f1[0], f1[1]); A1.u.y = pkh2(f1[2], f1[3]);
            A1.u.z = pkh2(f1[4], f1[5]); A1.u.w = pkh2(f1[6], f1[7]);
        }

        const uint4* w1f4 = (const uint4*)w1f;
        #pragma unroll
        for (int n0 = 0; n0 < 4; ++n0) {
            union { uint4 u; f16x8 h; } Bh, Bl;
            Bh.u = w1f4[(n0 * 2 + 0) * 64 + lane];
            Bl.u = w1f4[(n0 * 2 + 1) * 64 + lane];
            f32x4 acc0 = {0.f, 0.f, 0.f, 0.f};
            f32x4 acc1 = {0.f, 0.f, 0.f, 0.f};
            acc0 = __builtin_amdgcn_mfma_f32_16x16x32_f16(A0.h, Bh.h, acc0, 0, 0, 0);
            acc0 = __builtin_amdgcn_mfma_f32_16x16x32_f16(A0.h, Bl.h, acc0, 0, 0, 0);
            acc1 = __builtin_amdgcn_mfma_f32_16x16x32_f16(A1.h, Bh.h, acc1, 0, 0, 0);
            acc1 = __builtin_amdgcn_mfma_f32_16x16x32_f16(A1.h, Bl.h, acc1, 0, 0, 0);

            // epilogue: hid = n0*16+l15; D row = sample m*16 + l4*4 + r
            int hid = n0 * 16 + l15;
            float bv = b1[hid];
            int bblk = hid >> 3;               // 16B block index within s_h row
            int hoff = hid & 7;
            #pragma unroll
            for (int m = 0; m < 2; ++m) {
                f32x4 acc = m ? acc1 : acc0;
                #pragma unroll
                for (int r = 0; r < 4; ++r) {
                    int smp = halfu * 32 + m * 16 + l4 * 4 + r;
                    float hv = softplusf(acc[r] + bv);
                    int blk = bblk ^ (smp & 7);
                    *(unsigned short*)((char*)s_h + smp * 128 + blk * 16 + hoff * 2) = f2h(hv);
                }
            }
        }
    }
    __syncthreads();   // h complete; s_feat dead (s_rgb may alias it now)

    // ---- GEMM2 via MFMA 16x16x32 f16 (unchanged from R23) ----
    {
        const uint4* w2f4 = (const uint4*)w2f;
        int gbase = blockIdx.x * 64;

        #pragma unroll
        for (int n0 = 0; n0 < 3; ++n0) {
            f32x4 acc0 = {0.f, 0.f, 0.f, 0.f};
            f32x4 acc1 = {0.f, 0.f, 0.f, 0.f};
            #pragma unroll
            for (int k0 = 0; k0 < 2; ++k0) {
                union { uint4 u; f16x8 h; } Bh, Bl;
                Bh.u = w2f4[((k0 * 3 + n0) * 2 + 0) * 64 + lane];
                Bl.u = w2f4[((k0 * 3 + n0) * 2 + 1) * 64 + lane];
                #pragma unroll
                for (int m = 0; m < 2; ++m) {
                    int rowi = halfu * 32 + m * 16 + l15;
                    int blk = (k0 * 4 + l4) ^ (rowi & 7);
                    union { uint4 u; f16x8 h; } A;
                    A.u = *(const uint4*)((const char*)s_h + rowi * 128 + blk * 16);
                    if (m == 0) {
                        acc0 = __builtin_amdgcn_mfma_f32_16x16x32_f16(A.h, Bh.h, acc0, 0, 0, 0);
                        acc0 = __builtin_amdgcn_mfma_f32_16x16x32_f16(A.h, Bl.h, acc0, 0, 0, 0);
                    } else {
                        acc1 = __builtin_amdgcn_mfma_f32_16x16x32_f16(A.h, Bh.h, acc1, 0, 0, 0);
                        acc1 = __builtin_amdgcn_mfma_f32_16x16x32_f16(A.h, Bl.h, acc1, 0, 0, 0);
                    }
                }
            }
            // epilogue for this n0: D layout col=l&15 (out ch), row=(l>>4)*4+reg (sample)
            int nn = n0 * 16 + l15;
            float bv = (nn < ODIM) ? b2[nn] : 0.f;
            #pragma unroll
            for (int m = 0; m < 2; ++m) {
                f32x4 acc = m ? acc1 : acc0;
                #pragma unroll
                for (int r = 0; r < 4; ++r) {
                    float val = acc[r] + bv;
                    int sl_ = halfu * 32 + m * 16 + l4 * 4 + r;
                    if (n0 == 0 && l15 == 0) sigma_out[gbase + sl_] = val;
                    if (nn >= 1 && nn < ODIM) s_rgb[sl_ * 32 + (nn - 1)] = f2h(sigact(val));
                }
            }
        }
    }
    __syncthreads();   // rgb staged for all 64 samples

    // cooperative coalesced fp16 rgb store: 64 samples x 32 halves = 4 KB
    {
        uint4* dst = (uint4*)(rgb_out + (size_t)blockIdx.x * 64 * 32);
        const uint4* src = (const uint4*)s_rgb;
        #pragma unroll
        for (int i = 0; i < 2; ++i) {
            int u = i * 128 + tid;
            dst[u] = src[u];
        }
    }
}

// ---------------------------------------------------------------------------
// Kernel 3: importance sampling, one wave per ray; block-level minmax to
// scratch (bmin/bmax staged in the rgb_f region, overwritten by fine pass).
__global__ __launch_bounds__(256) void importance_kernel(
    const float* __restrict__ depth_c, const float* __restrict__ sigma_c,
    const float* __restrict__ noise_imp, float* __restrict__ depth_f,
    float* __restrict__ bmin, float* __restrict__ bmax)
{
    __shared__ float s_cdf[4][46];
    __shared__ float s_bins[4][47];
    __shared__ float s_red[8];
    int wave = threadIdx.x >> 6, lane = threadIdx.x & 63;
    int ray = blockIdx.x * 4 + wave;

    const float* d  = depth_c + (size_t)ray * SC;
    const float* sg = sigma_c + (size_t)ray * SC;
    float dval = (lane < SC) ? d[lane] : 0.f;
    float sval = (lane < SC) ? sg[lane] : 0.f;
    float dnext = __shfl_down(dval, 1);
    float snext = __shfl_down(sval, 1);

    float a = 0.f;
    if (lane < SC-1) {
        float dens = softplusf(0.5f * (sval + snext) - 1.f);
        a = 1.f - expf(-dens * (dnext - dval));
    }
    float f = (lane < SC-1) ? (1.f - a + 1e-10f) : 1.f;
    float incl = f;
    #pragma unroll
    for (int off = 1; off < 64; off <<= 1) {
        float t = __shfl_up(incl, off);
        if (lane >= off) incl *= t;
    }
    float T = (lane == 0) ? 1.f : __shfl_up(incl, 1);
    float w = a * T;
    float wm1 = __shfl_up(w, 1);
    float wp1 = __shfl_down(w, 1);
    float wn = 0.5f * (fmaxf(wm1, w) + fmaxf(w, wp1)) + 0.01f + 1e-5f;
    float g = (lane >= 1 && lane <= 45) ? wn : 0.f;
    float incl2 = g;
    #pragma unroll
    for (int off = 1; off < 64; off <<= 1) {
        float t = __shfl_up(incl2, off);
        if (lane >= off) incl2 += t;
    }
    float sum = __shfl(incl2, 45);
    if (lane == 0) s_cdf[wave][0] = 0.f;
    else if (lane <= 45) s_cdf[wave][lane] = incl2 / sum;
    if (lane < SC-1) s_bins[wave][lane] = 0.5f * (dval + dnext);
    __syncthreads();

    float fmn = 1e30f, fmx = -1e30f;
    if (lane < SC) {
        float u = noise_imp[(size_t)ray * SC + lane];
        int inds = 0;
        #pragma unroll
        for (int t = 0; t < 46; ++t) inds += (s_cdf[wave][t] <= u) ? 1 : 0;
        int below = max(inds - 1, 0), above = min(inds, 45);
        float cb = s_cdf[wave][below], ca = s_cdf[wave][above];
        float bb = s_bins[wave][below], ba = s_bins[wave][above];
        float den = (ca - cb < 1e-5f) ? 1.f : (ca - cb);
        float s = bb + (u - cb) / den * (ba - bb);
        depth_f[(size_t)ray * SC + lane] = s;
        fmn = s; fmx = s;
    }
    float d0 = __shfl(dval, 0), dlast = __shfl(dval, SC-1);
    fmn = fminf(fmn, d0); fmx = fmaxf(fmx, dlast);
    #pragma unroll
    for (int off = 32; off >= 1; off >>= 1) {
        fmn = fminf(fmn, __shfl_xor(fmn, off));
        fmx = fmaxf(fmx, __shfl_xor(fmx, off));
    }
    if (lane == 0) { s_red[wave] = fmn; s_red[4 + wave] = fmx; }
    __syncthreads();
    if (threadIdx.x == 0) {
        bmin[blockIdx.x] = fminf(fminf(s_red[0], s_red[1]), fminf(s_red[2], s_red[3]));
        bmax[blockIdx.x] = fmaxf(fmaxf(s_red[4], s_red[5]), fmaxf(s_red[6], s_red[7]));
    }
}

// ---------------------------------------------------------------------------
// Kernel 3b: fold 2048 per-block (min,max) pairs into minmax[0..1]. 1 block.
__global__ __launch_bounds__(1024) void reduce_minmax(
    const float* __restrict__ bmin, const float* __restrict__ bmax,
    unsigned int* __restrict__ minmax)
{
    int tid = threadIdx.x;
    float mn = fminf(bmin[tid], bmin[tid + 1024]);
    float mx = fmaxf(bmax[tid], bmax[tid + 1024]);
    #pragma unroll
    for (int off = 32; off >= 1; off >>= 1) {
        mn = fminf(mn, __shfl_xor(mn, off));
        mx = fmaxf(mx, __shfl_xor(mx, off));
    }
    __shared__ float smn[16], smx[16];
    int wv = tid >> 6;
    if ((tid & 63) == 0) { smn[wv] = mn; smx[wv] = mx; }
    __syncthreads();
    if (tid == 0) {
        float m = smn[0], M = smx[0];
        #pragma unroll
        for (int i = 1; i < 16; ++i) { m = fminf(m, smn[i]); M = fmaxf(M, smx[i]); }
        minmax[0] = __float_as_uint(m);
        minmax[1] = __float_as_uint(M);
    }
}

// ---------------------------------------------------------------------------
// Kernel 4: merge coarse+fine (stable rank sort of 96), final ray-march.
// rgb inputs fp16.
__global__ __launch_bounds__(256) void final_march(
    const float* __restrict__ depth_c, const float* __restrict__ sigma_c,
    const unsigned short* __restrict__ rgb_c,
    const float* __restrict__ depth_f, const float* __restrict__ sigma_f,
    const unsigned short* __restrict__ rgb_f,
    const unsigned int* __restrict__ minmax,
    float* __restrict__ out)
{
    __shared__ float dall[4][96];
    __shared__ float sall[4][96];
    __shared__ float dsrt[4][96];
    __shared__ float ssrt[4][96];
    __shared__ int   perm[4][96];
    __shared__ float al[4][96];

    int wid = threadIdx.x >> 6, lane = threadIdx.x & 63;
    int ray = blockIdx.x * 4 + wid;

    for (int j = lane; j < 96; j += 64) {
        float dv, sv;
        if (j < 48) { dv = depth_c[(size_t)ray*48 + j]; sv = sigma_c[(size_t)ray*48 + j]; }
        else        { dv = depth_f[(size_t)ray*48 + j-48]; sv = sigma_f[(size_t)ray*48 + j-48]; }
        dall[wid][j] = dv; sall[wid][j] = sv;
    }
    __syncthreads();
    for (int j = lane; j < 96; j += 64) {
        float dj = dall[wid][j];
        int rank = 0;
        for (int k = 0; k < 96; ++k) {
            float dk = dall[wid][k];
            rank += (dk < dj || (dk == dj && k < j)) ? 1 : 0;
        }
        dsrt[wid][rank] = dj;
        ssrt[wid][rank] = sall[wid][j];
        perm[wid][rank] = j;
    }
    __syncthreads();
    for (int i = lane; i < 95; i += 64) {
        float dlt = dsrt[wid][i+1] - dsrt[wid][i];
        float dens = softplusf(0.5f * (ssrt[wid][i] + ssrt[wid][i+1]) - 1.f);
        al[wid][i] = 1.f - expf(-dens * dlt);
    }
    __syncthreads();
    if (lane == 0) {
        float T = 1.f, wsum = 0.f, dsum = 0.f;
        for (int i = 0; i < 95; ++i) {
            float a = al[wid][i];
            float wloc = a * T;
            T *= 1.f - a + 1e-10f;
            al[wid][i] = wloc;
            wsum += wloc;
            dsum += wloc * 0.5f * (dsrt[wid][i] + dsrt[wid][i+1]);
        }
        float depth = dsum / wsum;
        if (isnan(depth)) depth = INFINITY;
        float gmn = __uint_as_float(minmax[0]);
        float gmx = __uint_as_float(minmax[1]);
        depth = fminf(fmaxf(depth, gmn), gmx);
        out[262144 + ray] = depth;
        out[270336 + ray] = wsum;
        out[278528 + ray] = T;
    }
    __syncthreads();
    int k = lane & 31, half = lane >> 5;
    int i0 = half * 48, i1 = half ? 95 : 48;
    const unsigned short* rc = rgb_c + (size_t)ray * 48 * 32;
    const unsigned short* rf = rgb_f + (size_t)ray * 48 * 32;
    float acc = 0.f;
    int j0 = perm[wid][i0];
    float cur = (j0 < 48) ? h2f(rc[j0*32 + k]) : h2f(rf[(j0-48)*32 + k]);
    for (int i = i0; i < i1; ++i) {
        int jn = perm[wid][i+1];
        float nxt = (jn < 48) ? h2f(rc[jn*32 + k]) : h2f(rf[(jn-48)*32 + k]);
        acc += al[wid][i] * (cur + nxt);
        cur = nxt;
    }
    acc *= 0.5f;
    acc += __shfl_xor(acc, 32);
    if (half == 0) out[(size_t)ray * 32 + k] = acc * 2.f - 1.f;
}

// ---------------------------------------------------------------------------
extern "C" void kernel_launch(void* const* d_in, const int* in_sizes, int n_in,
                              void* d_out, int out_size, void* d_ws, size_t ws_size,
                              hipStream_t stream) {
    const float* planes      = (const float*)d_in[0];
    const float* origins     = (const float*)d_in[1];
    const float* dirs        = (const float*)d_in[2];
    const float* w1          = (const float*)d_in[3];
    const float* b1          = (const float*)d_in[4];
    const float* w2          = (const float*)d_in[5];
    const float* b2          = (const float*)d_in[6];
    const float* noise_strat = (const float*)d_in[7];
    const float* noise_imp   = (const float*)d_in[8];
    float* out = (float*)d_out;
    float* ws  = (float*)d_ws;

    unsigned short* planes_bf = (unsigned short*)(ws + OFF_PLANES2);
    float* w2f = ws + OFF_W2F;
    float* w1f = ws + OFF_W1F;
    float* depth_c = ws + OFF_DEPTH_C;
    float* sigma_c = ws + OFF_SIGMA_C;
    unsigned short* rgb_c = (unsigned short*)(ws + OFF_RGB_C);
    float* depth_f = ws + OFF_DEPTH_F;
    float* sigma_f = ws + OFF_SIGMA_F;
    unsigned short* rgb_f = (unsigned short*)(ws + OFF_RGB_F);
    unsigned int* minmax = (unsigned int*)(ws + OFF_MINMAX);
    // per-block minmax scratch: staged in the rgb_f region (overwritten by fine pass)
    float* bmin = (float*)rgb_f;
    float* bmax = (float*)rgb_f + 2048;

    precompute2<<<1536, 256, 0, stream>>>(planes, w1, w2, planes_bf, w2f, w1f);
    sample_mlp<<<NSAMP/64, 128, 0, stream>>>(planes_bf, nullptr, noise_strat, depth_c,
                                             origins, dirs, w1f, b1, w2f, b2,
                                             sigma_c, rgb_c, 1);
    importance_kernel<<<NRAY/4, 256, 0, stream>>>(depth_c, sigma_c, noise_imp,
                                                  depth_f, bmin, bmax);
    reduce_minmax<<<1, 1024, 0, stream>>>(bmin, bmax, minmax);
    sample_mlp<<<NSAMP/64, 128, 0, stream>>>(planes_bf, depth_f, nullptr, nullptr,
                                             origins, dirs, w1f, b1, w2f, b2,
                                             sigma_f, rgb_f, 0);
    final_march<<<NRAY/4, 256, 0, stream>>>(depth_c, sigma_c, rgb_c,
                                            depth_f, sigma_f, rgb_f, minmax, out);
}

// Round 15
// 265.583 us; speedup vs baseline: 2.9674x; 1.0076x over previous
//
#include <hip/hip_runtime.h>
#include <hip/hip_fp16.h>
#include <math.h>

// Problem constants
#define BB 2
#define RR 4096
#define NRAY (BB*RR)            // 8192
#define SC 48
#define NSAMP (NRAY*SC)         // 393216
#define CF 32
#define HID 64
#define ODIM 33                 // 1 sigma + 32 rgb
#define PRES 256
#define PLANE_HW (PRES*PRES)    // 65536
#define RAY_START 0.1f
#define RAY_END 2.0f
#define DELTA ((RAY_END-RAY_START)/(SC-1))

// workspace layout (in floats) — rgb regions hold fp16 (half the bytes used).
// planes_bf (bf16) uses only the first half of its fp32-sized slot; w2f/w1f
// (MFMA fragment buffers, hi/lo f16) live in the free second half.
#define OFF_PLANES2  ((size_t)0)
#define OFF_W2F      ((size_t)6291456)                  // 3072 floats
#define OFF_W1F      (OFF_W2F + 3072)                   // 2048 floats
#define OFF_DEPTH_C  ((size_t)12582912)                 // 393216
#define OFF_SIGMA_C  (OFF_DEPTH_C + 393216)             // 393216
#define OFF_RGB_C    (OFF_SIGMA_C + 393216)             // fp16
#define OFF_DEPTH_F  (OFF_RGB_C + 12582912)             // 393216
#define OFF_SIGMA_F  (OFF_DEPTH_F + 393216)             // 393216
#define OFF_RGB_F    (OFF_SIGMA_F + 393216)             // fp16
#define OFF_MINMAX   (OFF_RGB_F + 12582912)             // 2 uints (+2 pad)

typedef __attribute__((ext_vector_type(2))) float f2_t;
typedef __attribute__((ext_vector_type(4))) float f32x4;
typedef __attribute__((ext_vector_type(8))) _Float16 f16x8;

// packed fp32 FMA: acc.{x,y} += a.{x,y} * b.{x,y}  (one VOP3P inst = 2 FMA)
__device__ __forceinline__ void pk_fma_vv(f2_t& acc, f2_t a, f2_t b) {
    asm("v_pk_fma_f32 %0, %1, %2, %0" : "+v"(acc) : "v"(a), "v"(b));
}
// dword of 2 packed bf16 -> f2_t {lo, hi}
__device__ __forceinline__ f2_t bfpair(unsigned int u) {
    union { unsigned int i; float f; } lo, hi;
    lo.i = u << 16;
    hi.i = u & 0xffff0000u;
    f2_t r; r.x = lo.f; r.y = hi.f;
    return r;
}

__device__ __forceinline__ float softplusf(float x) {
    return fmaxf(x, 0.f) + __logf(1.f + __expf(-fabsf(x)));
}
__device__ __forceinline__ float sigact(float o) {
    float r = __builtin_amdgcn_rcpf(1.f + __expf(-o));
    return fmaf(1.002f, r, -0.001f);
}
__device__ __forceinline__ unsigned short f2bf(float f) {
    union { float f; unsigned int u; } v; v.f = f;
    unsigned int r = v.u + 0x7fffu + ((v.u >> 16) & 1u);   // RNE
    return (unsigned short)(r >> 16);
}
__device__ __forceinline__ unsigned int pack2(float lo, float hi) {
    return (unsigned int)f2bf(lo) | ((unsigned int)f2bf(hi) << 16);
}
// pack two floats to packed fp16 dword
__device__ __forceinline__ unsigned int pkh2(float a, float b) {
    __half2 h = __floats2half2_rn(a, b);
    union { __half2 h; unsigned int u; } cv; cv.h = h;
    return cv.u;
}
__device__ __forceinline__ unsigned short f2h(float a) {
    union { _Float16 h; unsigned short s; } cv; cv.h = (_Float16)a;
    return cv.s;
}
__device__ __forceinline__ float h2f(unsigned short h) {
    union { unsigned short s; __half h; } cv; cv.s = h;
    return __half2float(cv.h);
}
// fp16 bits -> float (defined before first use)
__device__ __forceinline__ float h2f_dev(unsigned short h) {
    union { unsigned short s; _Float16 h; } cv; cv.s = h;
    return (float)cv.h;
}

// ---------------------------------------------------------------------------
// Kernel 1: planes_bf[bp][y][x][c] = bf16(planes[bp][c][y][x]); plus MFMA
// fragment buffers: w2f (GEMM2 B, K=64: 2 k0 x 3 n0 x hi/lo) and w1f
// (GEMM1 B, K=32: 4 n0 x hi/lo). Fragment: lane l holds B[k-chunk l>>4, j]
// [n0*16 + (l&15)], k ascending within the 16B.
__global__ __launch_bounds__(256) void precompute2(
    const float* __restrict__ planes, const float* __restrict__ w1,
    const float* __restrict__ w2,
    unsigned short* __restrict__ planes_bf, float* __restrict__ w2f,
    float* __restrict__ w1f)
{
    if (blockIdx.x == 0 && threadIdx.x < 64) {
        int l = threadIdx.x;
        int l15 = l & 15, l4 = l >> 4;
        uint4* dst = (uint4*)w2f;
        for (int k0 = 0; k0 < 2; ++k0)
            for (int n0 = 0; n0 < 3; ++n0) {
                int n = n0 * 16 + l15;
                float v[8]; unsigned short hi[8], lo[8];
                #pragma unroll
                for (int j = 0; j < 8; ++j) {
                    int k = k0 * 32 + l4 * 8 + j;       // hid index
                    v[j] = (n < ODIM) ? w2[k * ODIM + n] : 0.f;
                    hi[j] = f2h(v[j]);
                    lo[j] = f2h(v[j] - h2f_dev(hi[j]));
                }
                uint4 uh, ul;
                uh.x = (unsigned int)hi[0] | ((unsigned int)hi[1] << 16);
                uh.y = (unsigned int)hi[2] | ((unsigned int)hi[3] << 16);
                uh.z = (unsigned int)hi[4] | ((unsigned int)hi[5] << 16);
                uh.w = (unsigned int)hi[6] | ((unsigned int)hi[7] << 16);
                ul.x = (unsigned int)lo[0] | ((unsigned int)lo[1] << 16);
                ul.y = (unsigned int)lo[2] | ((unsigned int)lo[3] << 16);
                ul.z = (unsigned int)lo[4] | ((unsigned int)lo[5] << 16);
                ul.w = (unsigned int)lo[6] | ((unsigned int)lo[7] << 16);
                dst[((k0 * 3 + n0) * 2 + 0) * 64 + l] = uh;
                dst[((k0 * 3 + n0) * 2 + 1) * 64 + l] = ul;
            }
    }
    if (blockIdx.x == 1 && threadIdx.x < 64) {
        int l = threadIdx.x;
        int l15 = l & 15, l4 = l >> 4;
        uint4* dst = (uint4*)w1f;
        for (int n0 = 0; n0 < 4; ++n0) {
            int n = n0 * 16 + l15;
            float v[8]; unsigned short hi[8], lo[8];
            #pragma unroll
            for (int j = 0; j < 8; ++j) {
                int k = l4 * 8 + j;                     // feature index (K=32)
                v[j] = w1[k * HID + n];
                hi[j] = f2h(v[j]);
                lo[j] = f2h(v[j] - h2f_dev(hi[j]));
            }
            uint4 uh, ul;
            uh.x = (unsigned int)hi[0] | ((unsigned int)hi[1] << 16);
            uh.y = (unsigned int)hi[2] | ((unsigned int)hi[3] << 16);
            uh.z = (unsigned int)hi[4] | ((unsigned int)hi[5] << 16);
            uh.w = (unsigned int)hi[6] | ((unsigned int)hi[7] << 16);
            ul.x = (unsigned int)lo[0] | ((unsigned int)lo[1] << 16);
            ul.y = (unsigned int)lo[2] | ((unsigned int)lo[3] << 16);
            ul.z = (unsigned int)lo[4] | ((unsigned int)lo[5] << 16);
            ul.w = (unsigned int)lo[6] | ((unsigned int)lo[7] << 16);
            dst[(n0 * 2 + 0) * 64 + l] = uh;
            dst[(n0 * 2 + 1) * 64 + l] = ul;
        }
    }
    int row = blockIdx.x;
    int bp = row >> 8, y = row & 255;
    int x = threadIdx.x;
    const float* src = planes + (size_t)bp * CF * PLANE_HW + (size_t)y * PRES + x;
    unsigned short* dst = planes_bf + ((size_t)bp * PLANE_HW + (size_t)(y << 8) + x) * CF;
    #pragma unroll
    for (int q = 0; q < 4; ++q) {
        uint4 u;
        u.x = pack2(src[(size_t)(q*8+0)*PLANE_HW], src[(size_t)(q*8+1)*PLANE_HW]);
        u.y = pack2(src[(size_t)(q*8+2)*PLANE_HW], src[(size_t)(q*8+3)*PLANE_HW]);
        u.z = pack2(src[(size_t)(q*8+4)*PLANE_HW], src[(size_t)(q*8+5)*PLANE_HW]);
        u.w = pack2(src[(size_t)(q*8+6)*PLANE_HW], src[(size_t)(q*8+7)*PLANE_HW]);
        ((uint4*)dst)[q] = u;
    }
}

// ---------------------------------------------------------------------------
// Kernel 2 (unchanged R24): gather + both GEMMs on MFMA.
__global__ __launch_bounds__(128, 3) void sample_mlp(
    const unsigned short* __restrict__ planes_bf,
    const float* __restrict__ depths_in,   // fine pass
    const float* __restrict__ noise,       // coarse pass
    float* __restrict__ depth_out,         // coarse pass
    const float* __restrict__ origins,
    const float* __restrict__ dirs,
    const float* __restrict__ w1f,
    const float* __restrict__ b1,
    const float* __restrict__ w2f, const float* __restrict__ b2,
    float* __restrict__ sigma_out, unsigned short* __restrict__ rgb_out,
    int coarse)
{
    __shared__ __align__(16) char s_mem[16640];
    float (*s_feat)[66] = (float (*)[66])s_mem;              // [32][66] = 8448 B (region A)
    unsigned short* s_h = (unsigned short*)(s_mem + 8448);   // [64][64] f16 = 8192 B (region B)
    unsigned short* s_rgb = (unsigned short*)s_mem;          // [64][32] f16 = 4096 B (aliases A)

    int tid = threadIdx.x;

    // ---- gather phase: quad qg = tid>>2 handles samples 2qg, 2qg+1 ----
    {
        int qg = tid >> 2, sl = tid & 3;             // qg in [0,32)
        int s0 = blockIdx.x * 64 + 2 * qg;           // even -> pair never straddles a ray
        int ray = s0 / SC;
        int b = ray >> 12;

        float dep[2];
        if (coarse) {
            int sb = s0 - ray * SC;
            dep[0] = RAY_START + (float)sb * DELTA + noise[s0] * DELTA;
            dep[1] = RAY_START + (float)(sb + 1) * DELTA + noise[s0 + 1] * DELTA;
            if (sl == 0) { depth_out[s0] = dep[0]; depth_out[s0 + 1] = dep[1]; }
        } else {
            dep[0] = depths_in[s0];
            dep[1] = depths_in[s0 + 1];
        }

        float ox = origins[ray*3+0], oy = origins[ray*3+1], oz = origins[ray*3+2];
        float dx = dirs[ray*3+0],    dy = dirs[ray*3+1],    dz = dirs[ray*3+2];

        f2_t fa[2][4];
        #pragma unroll
        for (int k = 0; k < 2; ++k)
            #pragma unroll
            for (int j = 0; j < 4; ++j) fa[k][j] = (f2_t){0.f, 0.f};

        #pragma unroll
        for (int k = 0; k < 2; ++k) {
            float cx = (ox + dep[k]*dx) * 0.5f;
            float cy = (oy + dep[k]*dy) * 0.5f;
            float cz = (oz + dep[k]*dz) * 0.5f;
            #pragma unroll
            for (int p = 0; p < 3; ++p) {
                float gx = (p == 0) ? cx : (p == 1) ? cy : cz;
                float gy = (p == 0) ? cy : (p == 1) ? cz : cx;
                float x = fmaf(gx, 128.f, 127.5f);
                float y = fmaf(gy, 128.f, 127.5f);
                float x0f = floorf(x), y0f = floorf(y);
                float wx1 = x - x0f, wy1 = y - y0f;
                int x0 = (int)x0f, y0 = (int)y0f;
                const unsigned short* pb = planes_bf + (size_t)(b*3 + p) * PLANE_HW * CF;
                #pragma unroll
                for (int cyi = 0; cyi < 2; ++cyi) {
                    #pragma unroll
                    for (int cxi = 0; cxi < 2; ++cxi) {
                        int xi = x0 + cxi, yi = y0 + cyi;
                        float wgt = ((cyi ? wy1 : 1.f - wy1) * (cxi ? wx1 : 1.f - wx1)) * (1.f/3.f);
                        if (xi < 0 || xi > 255 || yi < 0 || yi > 255) wgt = 0.f;
                        int xc = min(max(xi, 0), 255), yc = min(max(yi, 0), 255);
                        const uint4* tp = (const uint4*)(pb + (size_t)((yc << 8) + xc) * CF);
                        uint4 v = tp[sl];            // quad covers the 64B texel in 1 inst
                        f2_t wp2; wp2.x = wgt; wp2.y = wgt;
                        pk_fma_vv(fa[k][0], bfpair(v.x), wp2);
                        pk_fma_vv(fa[k][1], bfpair(v.y), wp2);
                        pk_fma_vv(fa[k][2], bfpair(v.z), wp2);
                        pk_fma_vv(fa[k][3], bfpair(v.w), wp2);
                    }
                }
            }
        }

        // stash: lane owns channels [8sl, 8sl+8) for its 2 samples
        #pragma unroll
        for (int k = 0; k < 2; ++k)
            #pragma unroll
            for (int j = 0; j < 4; ++j) {
                s_feat[8*sl + 2*j    ][2*qg + k] = fa[k][j].x;
                s_feat[8*sl + 2*j + 1][2*qg + k] = fa[k][j].y;
            }
    }
    __syncthreads();

    int lane = tid & 63;
    int halfu = __builtin_amdgcn_readfirstlane(tid >> 6);  // wave: samples [32h,32h+32)
    int l15 = lane & 15, l4 = lane >> 4;

    // ---- GEMM1 via MFMA: A from s_feat (fp32->f16), B from w1f ----
    {
        union { uint4 u; f16x8 h; } A0, A1;
        {
            int row0 = halfu * 32 + l15;       // m=0 tile sample row
            int row1 = row0 + 16;              // m=1 tile
            float f0[8], f1[8];
            #pragma unroll
            for (int j = 0; j < 8; ++j) {
                f0[j] = s_feat[l4*8 + j][row0];
                f1[j] = s_feat[l4*8 + j][row1];
            }
            A0.u.x = pkh2(f0[0], f0[1]); A0.u.y = pkh2(f0[2], f0[3]);
            A0.u.z = pkh2(f0[4], f0[5]); A0.u.w = pkh2(f0[6], f0[7]);
            A1.u.x = pkh2(f1[0], f1[1]); A1.u.y = pkh2(f1[2], f1[3]);
            A1.u.z = pkh2(f1[4], f1[5]); A1.u.w = pkh2(f1[6], f1[7]);
        }

        const uint4* w1f4 = (const uint4*)w1f;
        #pragma unroll
        for (int n0 = 0; n0 < 4; ++n0) {
            union { uint4 u; f16x8 h; } Bh, Bl;
            Bh.u = w1f4[(n0 * 2 + 0) * 64 + lane];
            Bl.u = w1f4[(n0 * 2 + 1) * 64 + lane];
            f32x4 acc0 = {0.f, 0.f, 0.f, 0.f};
            f32x4 acc1 = {0.f, 0.f, 0.f, 0.f};
            acc0 = __builtin_amdgcn_mfma_f32_16x16x32_f16(A0.h, Bh.h, acc0, 0, 0, 0);
            acc0 = __builtin_amdgcn_mfma_f32_16x16x32_f16(A0.h, Bl.h, acc0, 0, 0, 0);
            acc1 = __builtin_amdgcn_mfma_f32_16x16x32_f16(A1.h, Bh.h, acc1, 0, 0, 0);
            acc1 = __builtin_amdgcn_mfma_f32_16x16x32_f16(A1.h, Bl.h, acc1, 0, 0, 0);

            // epilogue: hid = n0*16+l15; D row = sample m*16 + l4*4 + r
            int hid = n0 * 16 + l15;
            float bv = b1[hid];
            int bblk = hid >> 3;               // 16B block index within s_h row
            int hoff = hid & 7;
            #pragma unroll
            for (int m = 0; m < 2; ++m) {
                f32x4 acc = m ? acc1 : acc0;
                #pragma unroll
                for (int r = 0; r < 4; ++r) {
                    int smp = halfu * 32 + m * 16 + l4 * 4 + r;
                    float hv = softplusf(acc[r] + bv);
                    int blk = bblk ^ (smp & 7);
                    *(unsigned short*)((char*)s_h + smp * 128 + blk * 16 + hoff * 2) = f2h(hv);
                }
            }
        }
    }
    __syncthreads();   // h complete; s_feat dead (s_rgb may alias it now)

    // ---- GEMM2 via MFMA 16x16x32 f16 ----
    {
        const uint4* w2f4 = (const uint4*)w2f;
        int gbase = blockIdx.x * 64;

        #pragma unroll
        for (int n0 = 0; n0 < 3; ++n0) {
            f32x4 acc0 = {0.f, 0.f, 0.f, 0.f};
            f32x4 acc1 = {0.f, 0.f, 0.f, 0.f};
            #pragma unroll
            for (int k0 = 0; k0 < 2; ++k0) {
                union { uint4 u; f16x8 h; } Bh, Bl;
                Bh.u = w2f4[((k0 * 3 + n0) * 2 + 0) * 64 + lane];
                Bl.u = w2f4[((k0 * 3 + n0) * 2 + 1) * 64 + lane];
                #pragma unroll
                for (int m = 0; m < 2; ++m) {
                    int rowi = halfu * 32 + m * 16 + l15;
                    int blk = (k0 * 4 + l4) ^ (rowi & 7);
                    union { uint4 u; f16x8 h; } A;
                    A.u = *(const uint4*)((const char*)s_h + rowi * 128 + blk * 16);
                    if (m == 0) {
                        acc0 = __builtin_amdgcn_mfma_f32_16x16x32_f16(A.h, Bh.h, acc0, 0, 0, 0);
                        acc0 = __builtin_amdgcn_mfma_f32_16x16x32_f16(A.h, Bl.h, acc0, 0, 0, 0);
                    } else {
                        acc1 = __builtin_amdgcn_mfma_f32_16x16x32_f16(A.h, Bh.h, acc1, 0, 0, 0);
                        acc1 = __builtin_amdgcn_mfma_f32_16x16x32_f16(A.h, Bl.h, acc1, 0, 0, 0);
                    }
                }
            }
            // epilogue for this n0: D layout col=l&15 (out ch), row=(l>>4)*4+reg (sample)
            int nn = n0 * 16 + l15;
            float bv = (nn < ODIM) ? b2[nn] : 0.f;
            #pragma unroll
            for (int m = 0; m < 2; ++m) {
                f32x4 acc = m ? acc1 : acc0;
                #pragma unroll
                for (int r = 0; r < 4; ++r) {
                    float val = acc[r] + bv;
                    int sl_ = halfu * 32 + m * 16 + l4 * 4 + r;
                    if (n0 == 0 && l15 == 0) sigma_out[gbase + sl_] = val;
                    if (nn >= 1 && nn < ODIM) s_rgb[sl_ * 32 + (nn - 1)] = f2h(sigact(val));
                }
            }
        }
    }
    __syncthreads();   // rgb staged for all 64 samples

    // cooperative coalesced fp16 rgb store: 64 samples x 32 halves = 4 KB
    {
        uint4* dst = (uint4*)(rgb_out + (size_t)blockIdx.x * 64 * 32);
        const uint4* src = (const uint4*)s_rgb;
        #pragma unroll
        for (int i = 0; i < 2; ++i) {
            int u = i * 128 + tid;
            dst[u] = src[u];
        }
    }
}

// ---------------------------------------------------------------------------
// Kernel 3: importance sampling, one wave per ray; block-level minmax to
// scratch (bmin/bmax staged in the rgb_f region, overwritten by fine pass).
__global__ __launch_bounds__(256) void importance_kernel(
    const float* __restrict__ depth_c, const float* __restrict__ sigma_c,
    const float* __restrict__ noise_imp, float* __restrict__ depth_f,
    float* __restrict__ bmin, float* __restrict__ bmax)
{
    __shared__ float s_cdf[4][46];
    __shared__ float s_bins[4][47];
    __shared__ float s_red[8];
    int wave = threadIdx.x >> 6, lane = threadIdx.x & 63;
    int ray = blockIdx.x * 4 + wave;

    const float* d  = depth_c + (size_t)ray * SC;
    const float* sg = sigma_c + (size_t)ray * SC;
    float dval = (lane < SC) ? d[lane] : 0.f;
    float sval = (lane < SC) ? sg[lane] : 0.f;
    float dnext = __shfl_down(dval, 1);
    float snext = __shfl_down(sval, 1);

    float a = 0.f;
    if (lane < SC-1) {
        float dens = softplusf(0.5f * (sval + snext) - 1.f);
        a = 1.f - expf(-dens * (dnext - dval));
    }
    float f = (lane < SC-1) ? (1.f - a + 1e-10f) : 1.f;
    float incl = f;
    #pragma unroll
    for (int off = 1; off < 64; off <<= 1) {
        float t = __shfl_up(incl, off);
        if (lane >= off) incl *= t;
    }
    float T = (lane == 0) ? 1.f : __shfl_up(incl, 1);
    float w = a * T;
    float wm1 = __shfl_up(w, 1);
    float wp1 = __shfl_down(w, 1);
    float wn = 0.5f * (fmaxf(wm1, w) + fmaxf(w, wp1)) + 0.01f + 1e-5f;
    float g = (lane >= 1 && lane <= 45) ? wn : 0.f;
    float incl2 = g;
    #pragma unroll
    for (int off = 1; off < 64; off <<= 1) {
        float t = __shfl_up(incl2, off);
        if (lane >= off) incl2 += t;
    }
    float sum = __shfl(incl2, 45);
    if (lane == 0) s_cdf[wave][0] = 0.f;
    else if (lane <= 45) s_cdf[wave][lane] = incl2 / sum;
    if (lane < SC-1) s_bins[wave][lane] = 0.5f * (dval + dnext);
    __syncthreads();

    float fmn = 1e30f, fmx = -1e30f;
    if (lane < SC) {
        float u = noise_imp[(size_t)ray * SC + lane];
        int inds = 0;
        #pragma unroll
        for (int t = 0; t < 46; ++t) inds += (s_cdf[wave][t] <= u) ? 1 : 0;
        int below = max(inds - 1, 0), above = min(inds, 45);
        float cb = s_cdf[wave][below], ca = s_cdf[wave][above];
        float bb = s_bins[wave][below], ba = s_bins[wave][above];
        float den = (ca - cb < 1e-5f) ? 1.f : (ca - cb);
        float s = bb + (u - cb) / den * (ba - bb);
        depth_f[(size_t)ray * SC + lane] = s;
        fmn = s; fmx = s;
    }
    float d0 = __shfl(dval, 0), dlast = __shfl(dval, SC-1);
    fmn = fminf(fmn, d0); fmx = fmaxf(fmx, dlast);
    #pragma unroll
    for (int off = 32; off >= 1; off >>= 1) {
        fmn = fminf(fmn, __shfl_xor(fmn, off));
        fmx = fmaxf(fmx, __shfl_xor(fmx, off));
    }
    if (lane == 0) { s_red[wave] = fmn; s_red[4 + wave] = fmx; }
    __syncthreads();
    if (threadIdx.x == 0) {
        bmin[blockIdx.x] = fminf(fminf(s_red[0], s_red[1]), fminf(s_red[2], s_red[3]));
        bmax[blockIdx.x] = fmaxf(fmaxf(s_red[4], s_red[5]), fmaxf(s_red[6], s_red[7]));
    }
}

// ---------------------------------------------------------------------------
// Kernel 3b: fold 2048 per-block (min,max) pairs into minmax[0..1]. 1 block.
__global__ __launch_bounds__(1024) void reduce_minmax(
    const float* __restrict__ bmin, const float* __restrict__ bmax,
    unsigned int* __restrict__ minmax)
{
    int tid = threadIdx.x;
    float mn = fminf(bmin[tid], bmin[tid + 1024]);
    float mx = fmaxf(bmax[tid], bmax[tid + 1024]);
    #pragma unroll
    for (int off = 32; off >= 1; off >>= 1) {
        mn = fminf(mn, __shfl_xor(mn, off));
        mx = fmaxf(mx, __shfl_xor(mx, off));
    }
    __shared__ float smn[16], smx[16];
    int wv = tid >> 6;
    if ((tid & 63) == 0) { smn[wv] = mn; smx[wv] = mx; }
    __syncthreads();
    if (tid == 0) {
        float m = smn[0], M = smx[0];
        #pragma unroll
        for (int i = 1; i < 16; ++i) { m = fminf(m, smn[i]); M = fmaxf(M, smx[i]); }
        minmax[0] = __float_as_uint(m);
        minmax[1] = __float_as_uint(M);
    }
}

// ---------------------------------------------------------------------------
// Kernel 4 (R26 resubmit): merge coarse+fine, final ray-march. Serial cumprod
// kept (known-good; two parallel-scan attempts both failed at 8.7e-2).
// O(96^2) rank-sort replaced by stable merge-rank using sorted coarse:
//   coarse j: rank = j + #{fine < d}            (fine idx > coarse idx -> strict)
//   fine  m:  rank = stable-rank-among-fine + #{coarse <= d}  (binary search)
// Per-lane compares drop 192 -> ~105. Cumprod + blend byte-identical to R24.
__global__ __launch_bounds__(256) void final_march(
    const float* __restrict__ depth_c, const float* __restrict__ sigma_c,
    const unsigned short* __restrict__ rgb_c,
    const float* __restrict__ depth_f, const float* __restrict__ sigma_f,
    const unsigned short* __restrict__ rgb_f,
    const unsigned int* __restrict__ minmax,
    float* __restrict__ out)
{
    __shared__ float dall[4][96];
    __shared__ float sall[4][96];
    __shared__ float dsrt[4][96];
    __shared__ float ssrt[4][96];
    __shared__ int   perm[4][96];
    __shared__ float al[4][96];

    int wid = threadIdx.x >> 6, lane = threadIdx.x & 63;
    int ray = blockIdx.x * 4 + wid;

    for (int j = lane; j < 96; j += 64) {
        float dv, sv;
        if (j < 48) { dv = depth_c[(size_t)ray*48 + j]; sv = sigma_c[(size_t)ray*48 + j]; }
        else        { dv = depth_f[(size_t)ray*48 + j-48]; sv = sigma_f[(size_t)ray*48 + j-48]; }
        dall[wid][j] = dv; sall[wid][j] = sv;
    }
    __syncthreads();
    for (int j = lane; j < 96; j += 64) {
        float dj = dall[wid][j];
        int rank;
        if (j < 48) {
            // coarse: position j among coarse (sorted, stable) + strict fine count
            int cnt = 0;
            for (int m = 0; m < 48; ++m)
                cnt += (dall[wid][48 + m] < dj) ? 1 : 0;
            rank = j + cnt;
        } else {
            // fine: stable rank among fine + #{coarse <= d} (coarse sorted)
            int mj = j - 48;
            int cnt = 0;
            for (int m = 0; m < 48; ++m) {
                float dm = dall[wid][48 + m];
                cnt += (dm < dj || (dm == dj && m < mj)) ? 1 : 0;
            }
            int lo = 0, hi = 48;
            while (lo < hi) {
                int mid = (lo + hi) >> 1;
                if (dall[wid][mid] <= dj) lo = mid + 1; else hi = mid;
            }
            rank = cnt + lo;
        }
        dsrt[wid][rank] = dj;
        ssrt[wid][rank] = sall[wid][j];
        perm[wid][rank] = j;
    }
    __syncthreads();
    for (int i = lane; i < 95; i += 64) {
        float dlt = dsrt[wid][i+1] - dsrt[wid][i];
        float dens = softplusf(0.5f * (ssrt[wid][i] + ssrt[wid][i+1]) - 1.f);
        al[wid][i] = 1.f - expf(-dens * dlt);
    }
    __syncthreads();
    if (lane == 0) {
        float T = 1.f, wsum = 0.f, dsum = 0.f;
        for (int i = 0; i < 95; ++i) {
            float a = al[wid][i];
            float wloc = a * T;
            T *= 1.f - a + 1e-10f;
            al[wid][i] = wloc;
            wsum += wloc;
            dsum += wloc * 0.5f * (dsrt[wid][i] + dsrt[wid][i+1]);
        }
        float depth = dsum / wsum;
        if (isnan(depth)) depth = INFINITY;
        float gmn = __uint_as_float(minmax[0]);
        float gmx = __uint_as_float(minmax[1]);
        depth = fminf(fmaxf(depth, gmn), gmx);
        out[262144 + ray] = depth;
        out[270336 + ray] = wsum;
        out[278528 + ray] = T;
    }
    __syncthreads();
    int k = lane & 31, half = lane >> 5;
    int i0 = half * 48, i1 = half ? 95 : 48;
    const unsigned short* rc = rgb_c + (size_t)ray * 48 * 32;
    const unsigned short* rf = rgb_f + (size_t)ray * 48 * 32;
    float acc = 0.f;
    int j0 = perm[wid][i0];
    float cur = (j0 < 48) ? h2f(rc[j0*32 + k]) : h2f(rf[(j0-48)*32 + k]);
    for (int i = i0; i < i1; ++i) {
        int jn = perm[wid][i+1];
        float nxt = (jn < 48) ? h2f(rc[jn*32 + k]) : h2f(rf[(jn-48)*32 + k]);
        acc += al[wid][i] * (cur + nxt);
        cur = nxt;
    }
    acc *= 0.5f;
    acc += __shfl_xor(acc, 32);
    if (half == 0) out[(size_t)ray * 32 + k] = acc * 2.f - 1.f;
}

// ---------------------------------------------------------------------------
extern "C" void kernel_launch(void* const* d_in, const int* in_sizes, int n_in,
                              void* d_out, int out_size, void* d_ws, size_t ws_size,
                              hipStream_t stream) {
    const float* planes      = (const float*)d_in[0];
    const float* origins     = (const float*)d_in[1];
    const float* dirs        = (const float*)d_in[2];
    const float* w1          = (const float*)d_in[3];
    const float* b1          = (const float*)d_in[4];
    const float* w2          = (const float*)d_in[5];
    const float* b2          = (const float*)d_in[6];
    const float* noise_strat = (const float*)d_in[7];
    const float* noise_imp   = (const float*)d_in[8];
    float* out = (float*)d_out;
    float* ws  = (float*)d_ws;

    unsigned short* planes_bf = (unsigned short*)(ws + OFF_PLANES2);
    float* w2f = ws + OFF_W2F;
    float* w1f = ws + OFF_W1F;
    float* depth_c = ws + OFF_DEPTH_C;
    float* sigma_c = ws + OFF_SIGMA_C;
    unsigned short* rgb_c = (unsigned short*)(ws + OFF_RGB_C);
    float* depth_f = ws + OFF_DEPTH_F;
    float* sigma_f = ws + OFF_SIGMA_F;
    unsigned short* rgb_f = (unsigned short*)(ws + OFF_RGB_F);
    unsigned int* minmax = (unsigned int*)(ws + OFF_MINMAX);
    // per-block minmax scratch: staged in the rgb_f region (overwritten by fine pass)
    float* bmin = (float*)rgb_f;
    float* bmax = (float*)rgb_f + 2048;

    precompute2<<<1536, 256, 0, stream>>>(planes, w1, w2, planes_bf, w2f, w1f);
    sample_mlp<<<NSAMP/64, 128, 0, stream>>>(planes_bf, nullptr, noise_strat, depth_c,
                                             origins, dirs, w1f, b1, w2f, b2,
                                             sigma_c, rgb_c, 1);
    importance_kernel<<<NRAY/4, 256, 0, stream>>>(depth_c, sigma_c, noise_imp,
                                                  depth_f, bmin, bmax);
    reduce_minmax<<<1, 1024, 0, stream>>>(bmin, bmax, minmax);
    sample_mlp<<<NSAMP/64, 128, 0, stream>>>(planes_bf, depth_f, nullptr, nullptr,
                                             origins, dirs, w1f, b1, w2f, b2,
                                             sigma_f, rgb_f, 0);
    final_march<<<NRAY/4, 256, 0, stream>>>(depth_c, sigma_c, rgb_c,
                                            depth_f, sigma_f, rgb_f, minmax, out);
}